// Round 1
// baseline (2991.910 us; speedup 1.0000x reference)
//
#include <hip/hip_runtime.h>
#include <hip/hip_bf16.h>

#define QROWS 4096
#define DDIM  768
#define NBANK 100000
#define CDIM  1000
#define KTOP  100
#define TKMAX 12288   // max chunk width staged in LDS by topk_partial (48KB)

typedef float floatx4 __attribute__((ext_vector_type(4)));
typedef short bf16x8 __attribute__((ext_vector_type(8)));

__device__ inline ushort f2bf(float f) {            // f32 -> bf16 RNE
  uint b = __float_as_uint(f);
  uint r = b + 0x7fffu + ((b >> 16) & 1u);
  return (ushort)(r >> 16);
}
__device__ inline uint f2ord(float f) {             // monotonic float->uint
  uint b = __float_as_uint(f);
  return (b & 0x80000000u) ? ~b : (b | 0x80000000u);
}
__device__ inline float ord2f(uint u) {
  uint b = (u & 0x80000000u) ? (u & 0x7fffffffu) : ~u;
  return __uint_as_float(b);
}

// ---------------- row-wise logsumexp (ncols <= 1024, %4==0), 1 wave/row ---
__global__ __launch_bounds__(256) void lse_rows(const float* __restrict__ x,
                                                float* __restrict__ out,
                                                int nrows, int ncols) {
  int row = blockIdx.x * 4 + (threadIdx.x >> 6);
  int lane = threadIdx.x & 63;
  if (row >= nrows) return;
  const float4* rp = (const float4*)(x + (size_t)row * ncols);
  int n4 = ncols >> 2;
  float4 v[4];
  float m = -3.0e38f;
#pragma unroll
  for (int j = 0; j < 4; j++) {
    int idx = lane + j * 64;
    if (idx < n4) {
      v[j] = rp[idx];
      m = fmaxf(m, fmaxf(fmaxf(v[j].x, v[j].y), fmaxf(v[j].z, v[j].w)));
    } else {
      v[j] = make_float4(-3.0e38f, -3.0e38f, -3.0e38f, -3.0e38f);
    }
  }
#pragma unroll
  for (int off = 32; off; off >>= 1) m = fmaxf(m, __shfl_xor(m, off));
  float s = 0.f;
#pragma unroll
  for (int j = 0; j < 4; j++)
    s += __expf(v[j].x - m) + __expf(v[j].y - m) +
         __expf(v[j].z - m) + __expf(v[j].w - m);
#pragma unroll
  for (int off = 32; off; off >>= 1) s += __shfl_xor(s, off);
  if (lane == 0) out[row] = m + __logf(s);
}

// ------------- scale[n] = conf[n] / ||bank_feas[n]||  (in place on conf) ---
__global__ __launch_bounds__(256) void row_scale(const float* __restrict__ feas,
                                                 float* __restrict__ cs, int nrows) {
  int row = blockIdx.x * 4 + (threadIdx.x >> 6);
  int lane = threadIdx.x & 63;
  if (row >= nrows) return;
  const float4* rp = (const float4*)(feas + (size_t)row * DDIM);
  float ss = 0.f;
#pragma unroll
  for (int j = 0; j < 3; j++) {
    float4 v = rp[lane + j * 64];
    ss += v.x * v.x + v.y * v.y + v.z * v.z + v.w * v.w;
  }
#pragma unroll
  for (int off = 32; off; off >>= 1) ss += __shfl_xor(ss, off);
  if (lane == 0) cs[row] = cs[row] / sqrtf(ss);
}

// ------------- a16[q][d] = bf16(feature/||feature||) ----------------------
__global__ __launch_bounds__(256) void feat_norm(const float* __restrict__ x,
                                                 ushort* __restrict__ y) {
  int row = blockIdx.x * 4 + (threadIdx.x >> 6);
  int lane = threadIdx.x & 63;
  if (row >= QROWS) return;
  const float4* rp = (const float4*)(x + (size_t)row * DDIM);
  float4 v[3];
  float ss = 0.f;
#pragma unroll
  for (int j = 0; j < 3; j++) {
    v[j] = rp[lane + j * 64];
    ss += v[j].x * v[j].x + v[j].y * v[j].y + v[j].z * v[j].z + v[j].w * v[j].w;
  }
#pragma unroll
  for (int off = 32; off; off >>= 1) ss += __shfl_xor(ss, off);
  float rn = 1.0f / sqrtf(ss);
  ushort4* dst = (ushort4*)(y + (size_t)row * DDIM);
#pragma unroll
  for (int j = 0; j < 3; j++)
    dst[lane + j * 64] = make_ushort4(f2bf(v[j].x * rn), f2bf(v[j].y * rn),
                                      f2bf(v[j].z * rn), f2bf(v[j].w * rn));
}

// ------------- b16[i][d] = bf16(bank_feas[n0+i]*scale), zero-pad rows -----
__global__ __launch_bounds__(256) void bank_conv(const float* __restrict__ feas,
                                                 const float* __restrict__ scale,
                                                 ushort* __restrict__ b16,
                                                 int n0, int len, int rows) {
  int i = blockIdx.x * 4 + (threadIdx.x >> 6);
  int lane = threadIdx.x & 63;
  if (i >= rows) return;
  ushort4* dst = (ushort4*)(b16 + (size_t)i * DDIM);
  if (i < len) {
    float s = scale[n0 + i];
    const float4* rp = (const float4*)(feas + (size_t)(n0 + i) * DDIM);
#pragma unroll
    for (int j = 0; j < 3; j++) {
      float4 v = rp[lane + j * 64];
      dst[lane + j * 64] = make_ushort4(f2bf(v.x * s), f2bf(v.y * s),
                                        f2bf(v.z * s), f2bf(v.w * s));
    }
  } else {
#pragma unroll
    for (int j = 0; j < 3; j++) dst[lane + j * 64] = make_ushort4(0, 0, 0, 0);
  }
}

// ------------- bf16 MFMA GEMM: sims[q][n] = a16 . b16^T (m97 structure) ---
#define BM 128
#define BN 128
#define BK 64

__device__ inline void load_lds16(const void* g, void* l) {
  __builtin_amdgcn_global_load_lds(
      (const __attribute__((address_space(1))) void*)g,
      (__attribute__((address_space(3))) void*)l, 16, 0, 0);
}

__global__ __launch_bounds__(256) void gemm_sims(const ushort* __restrict__ A,
                                                 const ushort* __restrict__ B,
                                                 float* __restrict__ C, int ldc) {
  __shared__ ushort sA[BM * BK];
  __shared__ ushort sB[BN * BK];
  const int tid = threadIdx.x;
  const int lane = tid & 63;
  const int wid = tid >> 6;
  const int wr = wid >> 1, wc = wid & 1;       // 2x2 waves, 64x64 each
  const int qBase = blockIdx.y * BM;
  const int nBase = blockIdx.x * BN;
  const int lr = tid >> 3;                     // 0..31 (row within 32-row round)
  const int lc = (tid & 7) * 8;                // col in elements

  floatx4 acc[4][4] = {};

  for (int k0 = 0; k0 < DDIM; k0 += BK) {
    __syncthreads();
#pragma unroll
    for (int r = 0; r < 4; r++) {
      int row = r * 32 + lr;
      load_lds16(A + (size_t)(qBase + row) * DDIM + k0 + lc, sA + row * BK + lc);
      load_lds16(B + (size_t)(nBase + row) * DDIM + k0 + lc, sB + row * BK + lc);
    }
    __syncthreads();
#pragma unroll
    for (int kk = 0; kk < 2; kk++) {
      bf16x8 af[4], bfr[4];
#pragma unroll
      for (int m = 0; m < 4; m++)
        af[m] = *(const bf16x8*)(sA + (wr * 64 + m * 16 + (lane & 15)) * BK +
                                 kk * 32 + (lane >> 4) * 8);
#pragma unroll
      for (int n = 0; n < 4; n++)
        bfr[n] = *(const bf16x8*)(sB + (wc * 64 + n * 16 + (lane & 15)) * BK +
                                  kk * 32 + (lane >> 4) * 8);
#pragma unroll
      for (int m = 0; m < 4; m++)
#pragma unroll
        for (int n = 0; n < 4; n++)
          acc[m][n] = __builtin_amdgcn_mfma_f32_16x16x32_bf16(af[m], bfr[n],
                                                              acc[m][n], 0, 0, 0);
    }
  }
#pragma unroll
  for (int m = 0; m < 4; m++)
#pragma unroll
    for (int n = 0; n < 4; n++) {
      int q = qBase + wr * 64 + m * 16 + (lane >> 4) * 4;
      int col = nBase + wc * 64 + n * 16 + (lane & 15);
      float* cp = C + (size_t)q * ldc + col;
#pragma unroll
      for (int r = 0; r < 4; r++) cp[(size_t)r * ldc] = acc[m][n][r];
    }
}

// ------------- exact radix-select threshold (block of 256) ----------------
__device__ uint radix_threshold(const uint* __restrict__ sv, int len, int kk0,
                                int t, int* hist, int* scan,
                                uint* shPrefix, int* shKk) {
  if (t == 0) { *shPrefix = 0u; *shKk = kk0; }
  __syncthreads();
  for (int pass = 0; pass < 4; pass++) {
    const int shift = 24 - pass * 8;
    hist[t] = 0;
    __syncthreads();
    uint prefix = *shPrefix;
    int kk = *shKk;
    uint pmask = pass ? (0xFFFFFFFFu << (shift + 8)) : 0u;
    for (int i = t; i < len; i += 256) {
      uint u = sv[i];
      if ((u & pmask) == prefix) atomicAdd(&hist[(u >> shift) & 0xffu], 1);
    }
    __syncthreads();
    scan[t] = hist[t];                 // suffix-sum scan: scan[t]=sum hist[t..255]
    __syncthreads();
    for (int off = 1; off < 256; off <<= 1) {
      int v = (t + off < 256) ? scan[t + off] : 0;
      __syncthreads();
      scan[t] += v;
      __syncthreads();
    }
    int above = (t < 255) ? scan[t + 1] : 0;
    if (above < kk && kk <= scan[t]) {
      *shPrefix = prefix | ((uint)t << shift);
      *shKk = kk - above;
    }
    __syncthreads();
  }
  return *shPrefix;
}

// ------------- per-chunk exact top-K multiset -> cand[q][slot*K .. ) -------
__global__ __launch_bounds__(256) void topk_partial(const float* __restrict__ sims,
                                                    int len, int ldc,
                                                    float* __restrict__ cand,
                                                    int slot) {
  __shared__ uint sv[TKMAX];
  __shared__ int hist[256], scan[256];
  __shared__ uint shPrefix;
  __shared__ int shKk, shM;
  const int t = threadIdx.x;
  const int q = blockIdx.x;
  const float* row = sims + (size_t)q * ldc;
  int len4 = len >> 2;
  for (int j = t; j < len4; j += 256) {
    float4 v = ((const float4*)row)[j];
    sv[j * 4 + 0] = f2ord(v.x); sv[j * 4 + 1] = f2ord(v.y);
    sv[j * 4 + 2] = f2ord(v.z); sv[j * 4 + 3] = f2ord(v.w);
  }
  for (int i = len4 * 4 + t; i < len; i += 256) sv[i] = f2ord(row[i]);
  if (t == 0) shM = 0;
  int kcl = len < KTOP ? len : KTOP;
  uint T = radix_threshold(sv, len, kcl, t, hist, scan, &shPrefix, &shKk);
  float* dst = cand + (size_t)q * (2 * KTOP) + slot * KTOP;
  for (int i = t; i < len; i += 256) {
    uint u = sv[i];
    if (u > T) { int p = atomicAdd(&shM, 1); dst[p] = ord2f(u); }
  }
  __syncthreads();
  int m = shM;
  for (int i = m + t; i < kcl; i += 256) dst[i] = ord2f(T);   // tie copies
  for (int i = kcl + t; i < KTOP; i += 256) dst[i] = -3.0e38f; // sentinels
}

// ------------- running merge: top-K of cand[q][0..2K) -> cand[q][0..K) ----
__global__ __launch_bounds__(256) void topk_merge(float* __restrict__ cand) {
  __shared__ uint sv[2 * KTOP];
  __shared__ int hist[256], scan[256];
  __shared__ uint shPrefix;
  __shared__ int shKk, shM;
  const int t = threadIdx.x, q = blockIdx.x;
  float* base = cand + (size_t)q * (2 * KTOP);
  if (t < 2 * KTOP) sv[t] = f2ord(base[t]);
  if (t == 0) shM = 0;
  uint T = radix_threshold(sv, 2 * KTOP, KTOP, t, hist, scan, &shPrefix, &shKk);
  for (int i = t; i < 2 * KTOP; i += 256) {
    uint u = sv[i];
    if (u > T) { int p = atomicAdd(&shM, 1); base[p] = ord2f(u); }
  }
  __syncthreads();
  int m = shM;
  for (int i = m + t; i < KTOP; i += 256) base[i] = ord2f(T);
}

// ------------- out[q] = -(mean topK) * energy[q] ---------------------------
__global__ __launch_bounds__(256) void finalize(const float* __restrict__ cand,
                                                const float* __restrict__ energy,
                                                float* __restrict__ out) {
  int q = blockIdx.x * 4 + (threadIdx.x >> 6);
  int lane = threadIdx.x & 63;
  if (q >= QROWS) return;
  const float* c = cand + (size_t)q * (2 * KTOP);
  float s = 0.f;
  for (int i = lane; i < KTOP; i += 64) s += c[i];
#pragma unroll
  for (int off = 32; off; off >>= 1) s += __shfl_xor(s, off);
  if (lane == 0) out[q] = -(s * (1.0f / KTOP)) * energy[q];
}

extern "C" void kernel_launch(void* const* d_in, const int* in_sizes, int n_in,
                              void* d_out, int out_size, void* d_ws, size_t ws_size,
                              hipStream_t stream) {
  const float* feature     = (const float*)d_in[0];
  const float* logit       = (const float*)d_in[1];
  const float* bank_feas   = (const float*)d_in[2];
  const float* bank_logits = (const float*)d_in[3];
  // d_in[4] is K (device scalar) — problem instance fixes K = 100 (KTOP).
  float* out = (float*)d_out;

  char* ws = (char*)d_ws;
  size_t off = 0;
  auto take = [&](size_t bytes) -> char* {
    char* p = ws + off;
    off = (off + bytes + 255) & ~(size_t)255;
    return p;
  };
  float*  energy = (float*)take((size_t)QROWS * 4);
  float*  scale  = (float*)take((size_t)NBANK * 4);
  ushort* a16    = (ushort*)take((size_t)QROWS * DDIM * 2);
  float*  cand   = (float*)take((size_t)QROWS * 2 * KTOP * 4);
  size_t fixedEnd = off;

  // choose chunk width Nc: multiple of 128, <= TKMAX, fitting b16 + sims in ws
  long long avail = (long long)ws_size - (long long)fixedEnd - 1024;
  long long per = (long long)DDIM * 2 + (long long)QROWS * 4; // bytes per column
  long long ncMax = avail > 0 ? avail / per : 0;
  int Nc = (int)(ncMax > TKMAX ? TKMAX : ncMax);
  Nc &= ~127;
  if (Nc < 128) return;  // workspace too small to run

  ushort* b16  = (ushort*)take((size_t)Nc * DDIM * 2);
  float*  sims = (float*)take((size_t)QROWS * Nc * 4);

  lse_rows <<<dim3((NBANK + 3) / 4), dim3(256), 0, stream>>>(bank_logits, scale, NBANK, CDIM);
  row_scale<<<dim3((NBANK + 3) / 4), dim3(256), 0, stream>>>(bank_feas, scale, NBANK);
  lse_rows <<<dim3((QROWS + 3) / 4), dim3(256), 0, stream>>>(logit, energy, QROWS, CDIM);
  feat_norm<<<dim3((QROWS + 3) / 4), dim3(256), 0, stream>>>(feature, a16);

  int nchunks = (NBANK + Nc - 1) / Nc;
  for (int c = 0; c < nchunks; c++) {
    int n0 = c * Nc;
    int len = NBANK - n0; if (len > Nc) len = Nc;
    int rows = ((len + 127) / 128) * 128;
    bank_conv<<<dim3((rows + 3) / 4), dim3(256), 0, stream>>>(bank_feas, scale, b16, n0, len, rows);
    dim3 g(rows / 128, QROWS / 128);
    gemm_sims<<<g, dim3(256), 0, stream>>>(a16, b16, sims, Nc);
    topk_partial<<<dim3(QROWS), dim3(256), 0, stream>>>(sims, len, Nc, cand, c ? 1 : 0);
    if (c) topk_merge<<<dim3(QROWS), dim3(256), 0, stream>>>(cand);
  }
  finalize<<<dim3((QROWS + 3) / 4), dim3(256), 0, stream>>>(cand, energy, out);
}

// Round 2
// 2337.776 us; speedup vs baseline: 1.2798x; 1.2798x over previous
//
#include <hip/hip_runtime.h>
#include <hip/hip_bf16.h>

#define QROWS 4096
#define DDIM  768
#define NBANK 100000
#define CDIM  1000
#define KTOP  100
#define NCHUNK 25088                 // sims chunk width (multiple of 128, %8==0)
#define NPAD  (4 * NCHUNK)           // 100352 padded bank rows

typedef float floatx4 __attribute__((ext_vector_type(4)));
typedef short bf16x8 __attribute__((ext_vector_type(8)));

__device__ inline ushort f2bf(float f) {            // f32 -> bf16 RNE
  uint b = __float_as_uint(f);
  uint r = b + 0x7fffu + ((b >> 16) & 1u);
  return (ushort)(r >> 16);
}
__device__ inline uint f2ord(float f) {             // monotonic f32->u32
  uint b = __float_as_uint(f);
  return (b & 0x80000000u) ? ~b : (b | 0x80000000u);
}
__device__ inline float ord2f(uint u) {
  uint b = (u & 0x80000000u) ? (u & 0x7fffffffu) : ~u;
  return __uint_as_float(b);
}
__device__ inline ushort ord16(ushort b) {          // monotonic bf16->u16
  return (b & 0x8000) ? (ushort)~b : (ushort)(b | 0x8000);
}
__device__ inline float o16f(ushort u) {            // u16 -> f32 value
  ushort b = (u & 0x8000) ? (ushort)(u & 0x7fff) : (ushort)~u;
  return __uint_as_float((uint)b << 16);
}

// ---- bank_prep: per bank row, conf=LSE(logits), scale=conf/||feas||,
// ----            b16[row] = bf16(feas*scale); zero rows >= NBANK ----------
__global__ __launch_bounds__(256) void bank_prep(const float* __restrict__ logits,
                                                 const float* __restrict__ feas,
                                                 ushort* __restrict__ b16) {
  int row = blockIdx.x * 4 + (threadIdx.x >> 6);
  int lane = threadIdx.x & 63;
  if (row >= NPAD) return;
  ushort4* dst = (ushort4*)(b16 + (size_t)row * DDIM);
  if (row >= NBANK) {
#pragma unroll
    for (int j = 0; j < 3; j++) dst[lane + j * 64] = make_ushort4(0, 0, 0, 0);
    return;
  }
  // logsumexp over the 1000-col logits row
  const float4* lp = (const float4*)(logits + (size_t)row * CDIM);
  float4 v[4];
  float m = -3.0e38f;
#pragma unroll
  for (int j = 0; j < 4; j++) {
    int idx = lane + j * 64;
    if (idx < CDIM / 4) {
      v[j] = lp[idx];
      m = fmaxf(m, fmaxf(fmaxf(v[j].x, v[j].y), fmaxf(v[j].z, v[j].w)));
    } else {
      v[j] = make_float4(-3.0e38f, -3.0e38f, -3.0e38f, -3.0e38f);
    }
  }
#pragma unroll
  for (int off = 32; off; off >>= 1) m = fmaxf(m, __shfl_xor(m, off));
  float s = 0.f;
#pragma unroll
  for (int j = 0; j < 4; j++)
    s += __expf(v[j].x - m) + __expf(v[j].y - m) +
         __expf(v[j].z - m) + __expf(v[j].w - m);
#pragma unroll
  for (int off = 32; off; off >>= 1) s += __shfl_xor(s, off);
  float conf = m + __logf(s);
  // norm of feas row, then scaled bf16 write
  const float4* fp = (const float4*)(feas + (size_t)row * DDIM);
  float4 w[3];
  float ss = 0.f;
#pragma unroll
  for (int j = 0; j < 3; j++) {
    w[j] = fp[lane + j * 64];
    ss += w[j].x * w[j].x + w[j].y * w[j].y + w[j].z * w[j].z + w[j].w * w[j].w;
  }
#pragma unroll
  for (int off = 32; off; off >>= 1) ss += __shfl_xor(ss, off);
  float scale = conf / sqrtf(ss);
#pragma unroll
  for (int j = 0; j < 3; j++)
    dst[lane + j * 64] = make_ushort4(f2bf(w[j].x * scale), f2bf(w[j].y * scale),
                                      f2bf(w[j].z * scale), f2bf(w[j].w * scale));
}

// ---- row-wise logsumexp for logit -> energy ------------------------------
__global__ __launch_bounds__(256) void lse_rows(const float* __restrict__ x,
                                                float* __restrict__ out,
                                                int nrows, int ncols) {
  int row = blockIdx.x * 4 + (threadIdx.x >> 6);
  int lane = threadIdx.x & 63;
  if (row >= nrows) return;
  const float4* rp = (const float4*)(x + (size_t)row * ncols);
  int n4 = ncols >> 2;
  float4 v[4];
  float m = -3.0e38f;
#pragma unroll
  for (int j = 0; j < 4; j++) {
    int idx = lane + j * 64;
    if (idx < n4) {
      v[j] = rp[idx];
      m = fmaxf(m, fmaxf(fmaxf(v[j].x, v[j].y), fmaxf(v[j].z, v[j].w)));
    } else {
      v[j] = make_float4(-3.0e38f, -3.0e38f, -3.0e38f, -3.0e38f);
    }
  }
#pragma unroll
  for (int off = 32; off; off >>= 1) m = fmaxf(m, __shfl_xor(m, off));
  float s = 0.f;
#pragma unroll
  for (int j = 0; j < 4; j++)
    s += __expf(v[j].x - m) + __expf(v[j].y - m) +
         __expf(v[j].z - m) + __expf(v[j].w - m);
#pragma unroll
  for (int off = 32; off; off >>= 1) s += __shfl_xor(s, off);
  if (lane == 0) out[row] = m + __logf(s);
}

// ---- a16[q][d] = bf16(feature/||feature||) -------------------------------
__global__ __launch_bounds__(256) void feat_norm(const float* __restrict__ x,
                                                 ushort* __restrict__ y) {
  int row = blockIdx.x * 4 + (threadIdx.x >> 6);
  int lane = threadIdx.x & 63;
  if (row >= QROWS) return;
  const float4* rp = (const float4*)(x + (size_t)row * DDIM);
  float4 v[3];
  float ss = 0.f;
#pragma unroll
  for (int j = 0; j < 3; j++) {
    v[j] = rp[lane + j * 64];
    ss += v[j].x * v[j].x + v[j].y * v[j].y + v[j].z * v[j].z + v[j].w * v[j].w;
  }
#pragma unroll
  for (int off = 32; off; off >>= 1) ss += __shfl_xor(ss, off);
  float rn = 1.0f / sqrtf(ss);
  ushort4* dst = (ushort4*)(y + (size_t)row * DDIM);
#pragma unroll
  for (int j = 0; j < 3; j++)
    dst[lane + j * 64] = make_ushort4(f2bf(v[j].x * rn), f2bf(v[j].y * rn),
                                      f2bf(v[j].z * rn), f2bf(v[j].w * rn));
}

// ---- bf16 MFMA GEMM (m97 structure), bf16 sims output --------------------
#define BM 128
#define BN 128
#define BK 64

__device__ inline void load_lds16(const void* g, void* l) {
  __builtin_amdgcn_global_load_lds(
      (const __attribute__((address_space(1))) void*)g,
      (__attribute__((address_space(3))) void*)l, 16, 0, 0);
}

__global__ __launch_bounds__(256) void gemm_sims(const ushort* __restrict__ A,
                                                 const ushort* __restrict__ B,
                                                 ushort* __restrict__ C) {
  __shared__ ushort sA[BM * BK];
  __shared__ ushort sB[BN * BK];
  const int tid = threadIdx.x;
  const int lane = tid & 63;
  const int wid = tid >> 6;
  const int wr = wid >> 1, wc = wid & 1;       // 2x2 waves, 64x64 each
  const int qBase = blockIdx.y * BM;
  const int nBase = blockIdx.x * BN;
  const int lr = tid >> 3;                     // 0..31
  const int lc = (tid & 7) * 8;                // col in elements

  floatx4 acc[4][4] = {};

  for (int k0 = 0; k0 < DDIM; k0 += BK) {
    __syncthreads();
#pragma unroll
    for (int r = 0; r < 4; r++) {
      int row = r * 32 + lr;
      load_lds16(A + (size_t)(qBase + row) * DDIM + k0 + lc, sA + row * BK + lc);
      load_lds16(B + (size_t)(nBase + row) * DDIM + k0 + lc, sB + row * BK + lc);
    }
    __syncthreads();
#pragma unroll
    for (int kk = 0; kk < 2; kk++) {
      bf16x8 af[4], bfr[4];
#pragma unroll
      for (int m = 0; m < 4; m++)
        af[m] = *(const bf16x8*)(sA + (wr * 64 + m * 16 + (lane & 15)) * BK +
                                 kk * 32 + (lane >> 4) * 8);
#pragma unroll
      for (int n = 0; n < 4; n++)
        bfr[n] = *(const bf16x8*)(sB + (wc * 64 + n * 16 + (lane & 15)) * BK +
                                  kk * 32 + (lane >> 4) * 8);
#pragma unroll
      for (int m = 0; m < 4; m++)
#pragma unroll
        for (int n = 0; n < 4; n++)
          acc[m][n] = __builtin_amdgcn_mfma_f32_16x16x32_bf16(af[m], bfr[n],
                                                              acc[m][n], 0, 0, 0);
    }
  }
#pragma unroll
  for (int m = 0; m < 4; m++)
#pragma unroll
    for (int n = 0; n < 4; n++) {
      int q = qBase + wr * 64 + m * 16 + (lane >> 4) * 4;
      int col = nBase + wc * 64 + n * 16 + (lane & 15);
      ushort* cp = C + (size_t)q * NCHUNK + col;
#pragma unroll
      for (int r = 0; r < 4; r++) cp[(size_t)r * NCHUNK] = f2bf(acc[m][n][r]);
    }
}

// ---- per-chunk exact top-K (16-bit keys, 2-pass radix) -------------------
__global__ __launch_bounds__(256) void topk16(const ushort* __restrict__ sims,
                                              int len, float* __restrict__ cand,
                                              int slot) {
  __shared__ ushort sv[NCHUNK];
  __shared__ int hist[256], scan[256];
  __shared__ int shHB, shKk, shT, shM;
  const int t = threadIdx.x;
  const int q = blockIdx.x;
  const ushort* row = sims + (size_t)q * NCHUNK;

  // stage row -> LDS as ordered u16, 8 elems (one uint4) per iteration
  int len8 = len >> 3;
  for (int j = t; j < len8; j += 256) {
    uint4 pk = ((const uint4*)row)[j];
    uint wsv[4] = {pk.x, pk.y, pk.z, pk.w};
    uint out[4];
#pragma unroll
    for (int e = 0; e < 4; e++) {
      uint u = wsv[e];
      uint mm = ((u >> 15) & 0x00010001u) * 0xffffu;   // 0xffff where sign set
      out[e] = (u ^ mm) | (0x80008000u & ~mm);
    }
    ((uint4*)sv)[j] = make_uint4(out[0], out[1], out[2], out[3]);
  }
  for (int i = (len8 << 3) + t; i < len; i += 256) sv[i] = ord16(row[i]);
  int kcl = len < KTOP ? len : KTOP;
  if (t == 0) { shHB = 0; shKk = kcl; }
  // ---- pass 1: high byte ----
  hist[t] = 0;
  __syncthreads();
  for (int i = t; i < len; i += 256) atomicAdd(&hist[sv[i] >> 8], 1);
  __syncthreads();
  scan[t] = hist[t];
  __syncthreads();
  for (int off = 1; off < 256; off <<= 1) {
    int v = (t + off < 256) ? scan[t + off] : 0;
    __syncthreads();
    scan[t] += v;
    __syncthreads();
  }
  {
    int above = (t < 255) ? scan[t + 1] : 0;
    int kk = kcl;
    if (above < kk && kk <= scan[t]) { shHB = t; shKk = kk - above; }
  }
  __syncthreads();
  int hb = shHB, kk2 = shKk;
  // ---- pass 2: low byte among high byte == hb ----
  hist[t] = 0;
  __syncthreads();
  for (int i = t; i < len; i += 256) {
    ushort u = sv[i];
    if ((u >> 8) == (uint)hb) atomicAdd(&hist[u & 0xff], 1);
  }
  __syncthreads();
  scan[t] = hist[t];
  __syncthreads();
  for (int off = 1; off < 256; off <<= 1) {
    int v = (t + off < 256) ? scan[t + off] : 0;
    __syncthreads();
    scan[t] += v;
    __syncthreads();
  }
  {
    int above = (t < 255) ? scan[t + 1] : 0;
    if (above < kk2 && kk2 <= scan[t]) shT = (hb << 8) | t;
    if (t == 0) shM = 0;
  }
  __syncthreads();
  ushort T = (ushort)shT;
  float* dst = cand + (size_t)q * (2 * KTOP) + slot * KTOP;
  for (int i = t; i < len; i += 256) {
    ushort u = sv[i];
    if (u > T) { int p = atomicAdd(&shM, 1); dst[p] = o16f(u); }
  }
  __syncthreads();
  int m = shM;
  for (int i = m + t; i < kcl; i += 256) dst[i] = o16f(T);      // tie copies
  for (int i = kcl + t; i < KTOP; i += 256) dst[i] = -3.0e38f;  // sentinels
}

// ---- f32 radix-select threshold (for the small 200-element merges) -------
__device__ uint radix_threshold(const uint* __restrict__ sv, int len, int kk0,
                                int t, int* hist, int* scan,
                                uint* shPrefix, int* shKk) {
  if (t == 0) { *shPrefix = 0u; *shKk = kk0; }
  __syncthreads();
  for (int pass = 0; pass < 4; pass++) {
    const int shift = 24 - pass * 8;
    hist[t] = 0;
    __syncthreads();
    uint prefix = *shPrefix;
    int kk = *shKk;
    uint pmask = pass ? (0xFFFFFFFFu << (shift + 8)) : 0u;
    for (int i = t; i < len; i += 256) {
      uint u = sv[i];
      if ((u & pmask) == prefix) atomicAdd(&hist[(u >> shift) & 0xffu], 1);
    }
    __syncthreads();
    scan[t] = hist[t];
    __syncthreads();
    for (int off = 1; off < 256; off <<= 1) {
      int v = (t + off < 256) ? scan[t + off] : 0;
      __syncthreads();
      scan[t] += v;
      __syncthreads();
    }
    int above = (t < 255) ? scan[t + 1] : 0;
    if (above < kk && kk <= scan[t]) {
      *shPrefix = prefix | ((uint)t << shift);
      *shKk = kk - above;
    }
    __syncthreads();
  }
  return *shPrefix;
}

// ---- running merge: top-K of cand[q][0..2K) -> cand[q][0..K) -------------
__global__ __launch_bounds__(256) void topk_merge(float* __restrict__ cand) {
  __shared__ uint sv[2 * KTOP];
  __shared__ int hist[256], scan[256];
  __shared__ uint shPrefix;
  __shared__ int shKk, shM;
  const int t = threadIdx.x, q = blockIdx.x;
  float* base = cand + (size_t)q * (2 * KTOP);
  if (t < 2 * KTOP) sv[t] = f2ord(base[t]);
  if (t == 0) shM = 0;
  uint T = radix_threshold(sv, 2 * KTOP, KTOP, t, hist, scan, &shPrefix, &shKk);
  for (int i = t; i < 2 * KTOP; i += 256) {
    uint u = sv[i];
    if (u > T) { int p = atomicAdd(&shM, 1); base[p] = ord2f(u); }
  }
  __syncthreads();
  int m = shM;
  for (int i = m + t; i < KTOP; i += 256) base[i] = ord2f(T);
}

// ---- out[q] = -(mean topK) * energy[q] -----------------------------------
__global__ __launch_bounds__(256) void finalize(const float* __restrict__ cand,
                                                const float* __restrict__ energy,
                                                float* __restrict__ out) {
  int q = blockIdx.x * 4 + (threadIdx.x >> 6);
  int lane = threadIdx.x & 63;
  if (q >= QROWS) return;
  const float* c = cand + (size_t)q * (2 * KTOP);
  float s = 0.f;
  for (int i = lane; i < KTOP; i += 64) s += c[i];
#pragma unroll
  for (int off = 32; off; off >>= 1) s += __shfl_xor(s, off);
  if (lane == 0) out[q] = -(s * (1.0f / KTOP)) * energy[q];
}

extern "C" void kernel_launch(void* const* d_in, const int* in_sizes, int n_in,
                              void* d_out, int out_size, void* d_ws, size_t ws_size,
                              hipStream_t stream) {
  const float* feature     = (const float*)d_in[0];
  const float* logit       = (const float*)d_in[1];
  const float* bank_feas   = (const float*)d_in[2];
  const float* bank_logits = (const float*)d_in[3];
  // d_in[4] is K (device scalar) — problem instance fixes K = 100 (KTOP).
  float* out = (float*)d_out;

  char* ws = (char*)d_ws;
  size_t off = 0;
  auto take = [&](size_t bytes) -> char* {
    char* p = ws + off;
    off = (off + bytes + 255) & ~(size_t)255;
    return p;
  };
  float*  energy = (float*)take((size_t)QROWS * 4);
  ushort* a16    = (ushort*)take((size_t)QROWS * DDIM * 2);
  float*  cand   = (float*)take((size_t)QROWS * 2 * KTOP * 4);
  ushort* b16    = (ushort*)take((size_t)NPAD * DDIM * 2);
  ushort* simsb  = (ushort*)take((size_t)QROWS * NCHUNK * 2);
  if (off > ws_size) return;  // workspace too small (needs ~370 MB)

  bank_prep<<<dim3(NPAD / 4), dim3(256), 0, stream>>>(bank_logits, bank_feas, b16);
  lse_rows <<<dim3(QROWS / 4), dim3(256), 0, stream>>>(logit, energy, QROWS, CDIM);
  feat_norm<<<dim3(QROWS / 4), dim3(256), 0, stream>>>(feature, a16);

  for (int c = 0; c < 4; c++) {
    int n0 = c * NCHUNK;
    int len = NBANK - n0; if (len > NCHUNK) len = NCHUNK;
    dim3 g(NCHUNK / BN, QROWS / BM);
    gemm_sims<<<g, dim3(256), 0, stream>>>(a16, b16 + (size_t)n0 * DDIM, simsb);
    topk16<<<dim3(QROWS), dim3(256), 0, stream>>>(simsb, len, cand, c ? 1 : 0);
    if (c) topk_merge<<<dim3(QROWS), dim3(256), 0, stream>>>(cand);
  }
  finalize<<<dim3(QROWS / 4), dim3(256), 0, stream>>>(cand, energy, out);
}

// Round 3
// 2097.484 us; speedup vs baseline: 1.4264x; 1.1146x over previous
//
#include <hip/hip_runtime.h>
#include <hip/hip_bf16.h>

#define QROWS 4096
#define DDIM  768
#define NBANK 100000
#define CDIM  1000
#define KTOP  100
#define NPAD  100352                 // 784*128, divisible by 2048 (512 thr * 4 u16)
#define TPB   512                    // topk_sum threads
#define UPT   49                     // uint2 per thread: 49*512*4 = 100352 u16
#define LCAP  20480                  // LDS candidate cap (40KB)

typedef float floatx4 __attribute__((ext_vector_type(4)));
typedef short bf16x8 __attribute__((ext_vector_type(8)));

__device__ inline ushort f2bf(float f) {            // f32 -> bf16 RNE
  uint b = __float_as_uint(f);
  uint r = b + 0x7fffu + ((b >> 16) & 1u);
  return (ushort)(r >> 16);
}
__device__ inline float o16f(ushort u) {            // ordered u16 -> f32 value
  ushort b = (u & 0x8000) ? (ushort)(u & 0x7fff) : (ushort)~u;
  return __uint_as_float((uint)b << 16);
}

// ---- bank_prep: conf=LSE(logits), b16[row]=bf16(feas*conf/||feas||) ------
__global__ __launch_bounds__(256) void bank_prep(const float* __restrict__ logits,
                                                 const float* __restrict__ feas,
                                                 ushort* __restrict__ b16) {
  int row = blockIdx.x * 4 + (threadIdx.x >> 6);
  int lane = threadIdx.x & 63;
  if (row >= NPAD) return;
  ushort4* dst = (ushort4*)(b16 + (size_t)row * DDIM);
  if (row >= NBANK) {
#pragma unroll
    for (int j = 0; j < 3; j++) dst[lane + j * 64] = make_ushort4(0, 0, 0, 0);
    return;
  }
  const float4* lp = (const float4*)(logits + (size_t)row * CDIM);
  float4 v[4];
  float m = -3.0e38f;
#pragma unroll
  for (int j = 0; j < 4; j++) {
    int idx = lane + j * 64;
    if (idx < CDIM / 4) {
      v[j] = lp[idx];
      m = fmaxf(m, fmaxf(fmaxf(v[j].x, v[j].y), fmaxf(v[j].z, v[j].w)));
    } else {
      v[j] = make_float4(-3.0e38f, -3.0e38f, -3.0e38f, -3.0e38f);
    }
  }
#pragma unroll
  for (int off = 32; off; off >>= 1) m = fmaxf(m, __shfl_xor(m, off));
  float s = 0.f;
#pragma unroll
  for (int j = 0; j < 4; j++)
    s += __expf(v[j].x - m) + __expf(v[j].y - m) +
         __expf(v[j].z - m) + __expf(v[j].w - m);
#pragma unroll
  for (int off = 32; off; off >>= 1) s += __shfl_xor(s, off);
  float conf = m + __logf(s);
  const float4* fp = (const float4*)(feas + (size_t)row * DDIM);
  float4 w[3];
  float ss = 0.f;
#pragma unroll
  for (int j = 0; j < 3; j++) {
    w[j] = fp[lane + j * 64];
    ss += w[j].x * w[j].x + w[j].y * w[j].y + w[j].z * w[j].z + w[j].w * w[j].w;
  }
#pragma unroll
  for (int off = 32; off; off >>= 1) ss += __shfl_xor(ss, off);
  float scale = conf / sqrtf(ss);
#pragma unroll
  for (int j = 0; j < 3; j++)
    dst[lane + j * 64] = make_ushort4(f2bf(w[j].x * scale), f2bf(w[j].y * scale),
                                      f2bf(w[j].z * scale), f2bf(w[j].w * scale));
}

// ---- row-wise logsumexp for logit -> energy ------------------------------
__global__ __launch_bounds__(256) void lse_rows(const float* __restrict__ x,
                                                float* __restrict__ out,
                                                int nrows, int ncols) {
  int row = blockIdx.x * 4 + (threadIdx.x >> 6);
  int lane = threadIdx.x & 63;
  if (row >= nrows) return;
  const float4* rp = (const float4*)(x + (size_t)row * ncols);
  int n4 = ncols >> 2;
  float4 v[4];
  float m = -3.0e38f;
#pragma unroll
  for (int j = 0; j < 4; j++) {
    int idx = lane + j * 64;
    if (idx < n4) {
      v[j] = rp[idx];
      m = fmaxf(m, fmaxf(fmaxf(v[j].x, v[j].y), fmaxf(v[j].z, v[j].w)));
    } else {
      v[j] = make_float4(-3.0e38f, -3.0e38f, -3.0e38f, -3.0e38f);
    }
  }
#pragma unroll
  for (int off = 32; off; off >>= 1) m = fmaxf(m, __shfl_xor(m, off));
  float s = 0.f;
#pragma unroll
  for (int j = 0; j < 4; j++)
    s += __expf(v[j].x - m) + __expf(v[j].y - m) +
         __expf(v[j].z - m) + __expf(v[j].w - m);
#pragma unroll
  for (int off = 32; off; off >>= 1) s += __shfl_xor(s, off);
  if (lane == 0) out[row] = m + __logf(s);
}

// ---- a16[q][d] = bf16(feature/||feature||) -------------------------------
__global__ __launch_bounds__(256) void feat_norm(const float* __restrict__ x,
                                                 ushort* __restrict__ y) {
  int row = blockIdx.x * 4 + (threadIdx.x >> 6);
  int lane = threadIdx.x & 63;
  if (row >= QROWS) return;
  const float4* rp = (const float4*)(x + (size_t)row * DDIM);
  float4 v[3];
  float ss = 0.f;
#pragma unroll
  for (int j = 0; j < 3; j++) {
    v[j] = rp[lane + j * 64];
    ss += v[j].x * v[j].x + v[j].y * v[j].y + v[j].z * v[j].z + v[j].w * v[j].w;
  }
#pragma unroll
  for (int off = 32; off; off >>= 1) ss += __shfl_xor(ss, off);
  float rn = 1.0f / sqrtf(ss);
  ushort4* dst = (ushort4*)(y + (size_t)row * DDIM);
#pragma unroll
  for (int j = 0; j < 3; j++)
    dst[lane + j * 64] = make_ushort4(f2bf(v[j].x * rn), f2bf(v[j].y * rn),
                                      f2bf(v[j].z * rn), f2bf(v[j].w * rn));
}

// ---- bf16 MFMA GEMM (m97 structure), supertile+XCD swizzle, bf16 out -----
#define BM 128
#define BN 128
#define BK 64
#define NWG (32 * 784)               // 25088 blocks, %8 == 0

__device__ inline void load_lds16(const void* g, void* l) {
  __builtin_amdgcn_global_load_lds(
      (const __attribute__((address_space(1))) void*)g,
      (__attribute__((address_space(3))) void*)l, 16, 0, 0);
}

__global__ __launch_bounds__(256) void gemm_sims(const ushort* __restrict__ A,
                                                 const ushort* __restrict__ B,
                                                 ushort* __restrict__ C) {
  __shared__ ushort sA[BM * BK];
  __shared__ ushort sB[BN * BK];
  // XCD-chunked (bijective: NWG%8==0) then 8x8 supertiles (3.1MB <= 4MB L2)
  int flat = blockIdx.x;
  int wgid = (flat & 7) * (NWG / 8) + (flat >> 3);
  int sup = wgid >> 6;                 // 0..391  (4 q-sup x 98 n-sup)
  int wi  = wgid & 63;
  int q_idx = ((sup & 3) << 3) | (wi & 7);    // 0..31
  int n_idx = ((sup >> 2) << 3) | (wi >> 3);  // 0..783
  const int qBase = q_idx * BM;
  const int nBase = n_idx * BN;

  const int tid = threadIdx.x;
  const int lane = tid & 63;
  const int wid = tid >> 6;
  const int wr = wid >> 1, wc = wid & 1;      // 2x2 waves, 64x64 each
  const int lr = tid >> 3;                    // 0..31
  const int lc = (tid & 7) * 8;               // col in elements

  floatx4 acc[4][4] = {};

  for (int k0 = 0; k0 < DDIM; k0 += BK) {
    __syncthreads();
#pragma unroll
    for (int r = 0; r < 4; r++) {
      int row = r * 32 + lr;
      load_lds16(A + (size_t)(qBase + row) * DDIM + k0 + lc, sA + row * BK + lc);
      load_lds16(B + (size_t)(nBase + row) * DDIM + k0 + lc, sB + row * BK + lc);
    }
    __syncthreads();
#pragma unroll
    for (int kk = 0; kk < 2; kk++) {
      bf16x8 af[4], bfr[4];
#pragma unroll
      for (int m = 0; m < 4; m++)
        af[m] = *(const bf16x8*)(sA + (wr * 64 + m * 16 + (lane & 15)) * BK +
                                 kk * 32 + (lane >> 4) * 8);
#pragma unroll
      for (int n = 0; n < 4; n++)
        bfr[n] = *(const bf16x8*)(sB + (wc * 64 + n * 16 + (lane & 15)) * BK +
                                  kk * 32 + (lane >> 4) * 8);
#pragma unroll
      for (int m = 0; m < 4; m++)
#pragma unroll
        for (int n = 0; n < 4; n++)
          acc[m][n] = __builtin_amdgcn_mfma_f32_16x16x32_bf16(af[m], bfr[n],
                                                              acc[m][n], 0, 0, 0);
    }
  }
#pragma unroll
  for (int m = 0; m < 4; m++)
#pragma unroll
    for (int n = 0; n < 4; n++) {
      int q = qBase + wr * 64 + m * 16 + (lane >> 4) * 4;
      int col = nBase + wc * 64 + n * 16 + (lane & 15);
      ushort* cp = C + (size_t)q * NPAD + col;
#pragma unroll
      for (int r = 0; r < 4; r++) cp[(size_t)r * NPAD] = f2bf(acc[m][n][r]);
    }
}

// ---- block reduction helpers (512 threads = 8 waves) ----------------------
__device__ inline int blk_reduce_i(int x, int* part) {
#pragma unroll
  for (int off = 32; off; off >>= 1) x += __shfl_xor(x, off);
  __syncthreads();
  if ((threadIdx.x & 63) == 0) part[threadIdx.x >> 6] = x;
  __syncthreads();
  int s = 0;
#pragma unroll
  for (int w = 0; w < 8; w++) s += part[w];
  return s;
}
__device__ inline float blk_reduce_f(float x, float* part) {
#pragma unroll
  for (int off = 32; off; off >>= 1) x += __shfl_xor(x, off);
  __syncthreads();
  if ((threadIdx.x & 63) == 0) part[threadIdx.x >> 6] = x;
  __syncthreads();
  float s = 0.f;
#pragma unroll
  for (int w = 0; w < 8; w++) s += part[w];
  return s;
}

// ---- fused exact top-K + mean + energy: one block per q-row ---------------
// Register-resident row (98 uints = 196 u16 keys/thread). L = 100th largest
// thread-max (provably <= T*), compact >=L to LDS, exact search there.
__global__ __launch_bounds__(TPB) void topk_sum(const ushort* __restrict__ sims,
                                                const float* __restrict__ energy,
                                                float* __restrict__ out) {
  __shared__ int ipart[8];
  __shared__ float fpart[8];
  __shared__ int shCand;
  __shared__ ushort slist[LCAP];
  const int t = threadIdx.x;
  const int q = blockIdx.x;
  const uint2* row = (const uint2*)(sims + (size_t)q * NPAD);

  uint v[2 * UPT];            // 98 uints, 2 ordered u16 keys each
#pragma unroll
  for (int r = 0; r < UPT; r++) {
    uint2 pk = row[r * TPB + t];
    uint u, mm;
    u = pk.x; mm = ((u >> 15) & 0x00010001u) * 0xffffu;
    v[2 * r] = (u ^ mm) | (0x80008000u & ~mm);
    u = pk.y; mm = ((u >> 15) & 0x00010001u) * 0xffffu;
    v[2 * r + 1] = (u ^ mm) | (0x80008000u & ~mm);
    if (r == UPT - 1 && t >= 424) { v[2 * r] = 0; v[2 * r + 1] = 0; }  // cols>=100000
  }
  // thread max key
  uint mx = 0;
#pragma unroll
  for (int r = 0; r < 2 * UPT; r++) {
    uint a = v[r] & 0xffffu, b = v[r] >> 16;
    mx = a > mx ? a : mx;
    mx = b > mx ? b : mx;
  }
  // L = 100th largest of the 512 thread maxima (binary search, 16 iters)
  uint lo = 1, hi = 65536;
  while (hi - lo > 1) {
    uint mid = (lo + hi) >> 1;
    int c = blk_reduce_i(mx >= mid ? 1 : 0, ipart);
    if (c >= KTOP) lo = mid; else hi = mid;
  }
  const uint L = lo;
  // compact keys >= L into LDS
  if (t == 0) shCand = 0;
  __syncthreads();
#pragma unroll
  for (int r = 0; r < 2 * UPT; r++) {
    uint a = v[r] & 0xffffu, b = v[r] >> 16;
    if (a >= L) { int p = atomicAdd(&shCand, 1); if (p < LCAP) slist[p] = (ushort)a; }
    if (b >= L) { int p = atomicAdd(&shCand, 1); if (p < LCAP) slist[p] = (ushort)b; }
  }
  __syncthreads();
  const int C = shCand;

  uint Tkey;
  float s = 0.f;
  int m = 0;
  if (C <= LCAP) {                         // fast path (expected)
    uint lo2 = L, hi2 = 65536;
    while (hi2 - lo2 > 1) {
      uint mid = (lo2 + hi2) >> 1;
      int c = 0;
      for (int i = t; i < C; i += TPB) c += ((uint)slist[i] >= mid) ? 1 : 0;
      c = blk_reduce_i(c, ipart);
      if (c >= KTOP) lo2 = mid; else hi2 = mid;
    }
    Tkey = lo2;
    for (int i = t; i < C; i += TPB) {
      uint u = slist[i];
      if (u > Tkey) { s += o16f((ushort)u); m++; }
    }
  } else {                                 // exact fallback over registers
    uint lo2 = L, hi2 = 65536;
    while (hi2 - lo2 > 1) {
      uint mid = (lo2 + hi2) >> 1;
      int c = 0;
#pragma unroll
      for (int r = 0; r < 2 * UPT; r++) {
        c += ((v[r] & 0xffffu) >= mid) ? 1 : 0;
        c += ((v[r] >> 16) >= mid) ? 1 : 0;
      }
      c = blk_reduce_i(c, ipart);
      if (c >= KTOP) lo2 = mid; else hi2 = mid;
    }
    Tkey = lo2;
#pragma unroll
    for (int r = 0; r < 2 * UPT; r++) {
      uint a = v[r] & 0xffffu, b = v[r] >> 16;
      if (a > Tkey) { s += o16f((ushort)a); m++; }
      if (b > Tkey) { s += o16f((ushort)b); m++; }
    }
  }
  m = blk_reduce_i(m, ipart);
  s = blk_reduce_f(s, fpart);
  if (t == 0) {
    float total = s + (float)(KTOP - m) * o16f((ushort)Tkey);   // tie fill
    out[q] = -(total * (1.0f / KTOP)) * energy[q];
  }
}

extern "C" void kernel_launch(void* const* d_in, const int* in_sizes, int n_in,
                              void* d_out, int out_size, void* d_ws, size_t ws_size,
                              hipStream_t stream) {
  const float* feature     = (const float*)d_in[0];
  const float* logit       = (const float*)d_in[1];
  const float* bank_feas   = (const float*)d_in[2];
  const float* bank_logits = (const float*)d_in[3];
  // d_in[4] is K (device scalar) — problem instance fixes K = 100 (KTOP).
  float* out = (float*)d_out;

  char* ws = (char*)d_ws;
  size_t off = 0;
  auto take = [&](size_t bytes) -> char* {
    char* p = ws + off;
    off = (off + bytes + 255) & ~(size_t)255;
    return p;
  };
  float*  energy = (float*)take((size_t)QROWS * 4);
  ushort* a16    = (ushort*)take((size_t)QROWS * DDIM * 2);
  ushort* b16    = (ushort*)take((size_t)NPAD * DDIM * 2);
  ushort* sims   = (ushort*)take((size_t)QROWS * NPAD * 2);
  if (off > ws_size) return;  // needs ~983 MB

  bank_prep<<<dim3(NPAD / 4), dim3(256), 0, stream>>>(bank_logits, bank_feas, b16);
  lse_rows <<<dim3(QROWS / 4), dim3(256), 0, stream>>>(logit, energy, QROWS, CDIM);
  feat_norm<<<dim3(QROWS / 4), dim3(256), 0, stream>>>(feature, a16);
  gemm_sims<<<dim3(NWG), dim3(256), 0, stream>>>(a16, b16, sims);
  topk_sum <<<dim3(QROWS), dim3(TPB), 0, stream>>>(sims, energy, out);
}

// Round 4
// 1744.763 us; speedup vs baseline: 1.7148x; 1.2022x over previous
//
#include <hip/hip_runtime.h>
#include <hip/hip_bf16.h>

#define QROWS 4096
#define DDIM  768
#define NBANK 100000
#define CDIM  1000
#define KTOP  100
#define NPAD  102400                 // padded bank cols: 400*256, 512*25*8
#define SEGW  25600                  // NPAD/4 keys per top-k segment
#define LCAP2 4096                   // LDS candidate cap in topk_seg

typedef float floatx4 __attribute__((ext_vector_type(4)));
typedef short bf16x8 __attribute__((ext_vector_type(8)));

__device__ inline ushort f2bf(float f) {            // f32 -> bf16 RNE
  uint b = __float_as_uint(f);
  uint r = b + 0x7fffu + ((b >> 16) & 1u);
  return (ushort)(r >> 16);
}
__device__ inline float o16f(ushort u) {            // ordered u16 -> f32 value
  ushort b = (u & 0x8000) ? (ushort)(u & 0x7fff) : (ushort)~u;
  return __uint_as_float((uint)b << 16);
}

// ---- bank_prep: conf=LSE(logits), b16[row]=bf16(feas*conf/||feas||) ------
__global__ __launch_bounds__(256) void bank_prep(const float* __restrict__ logits,
                                                 const float* __restrict__ feas,
                                                 ushort* __restrict__ b16) {
  int row = blockIdx.x * 4 + (threadIdx.x >> 6);
  int lane = threadIdx.x & 63;
  if (row >= NPAD) return;
  ushort4* dst = (ushort4*)(b16 + (size_t)row * DDIM);
  if (row >= NBANK) {
#pragma unroll
    for (int j = 0; j < 3; j++) dst[lane + j * 64] = make_ushort4(0, 0, 0, 0);
    return;
  }
  const float4* lp = (const float4*)(logits + (size_t)row * CDIM);
  float4 v[4];
  float m = -3.0e38f;
#pragma unroll
  for (int j = 0; j < 4; j++) {
    int idx = lane + j * 64;
    if (idx < CDIM / 4) {
      v[j] = lp[idx];
      m = fmaxf(m, fmaxf(fmaxf(v[j].x, v[j].y), fmaxf(v[j].z, v[j].w)));
    } else {
      v[j] = make_float4(-3.0e38f, -3.0e38f, -3.0e38f, -3.0e38f);
    }
  }
#pragma unroll
  for (int off = 32; off; off >>= 1) m = fmaxf(m, __shfl_xor(m, off));
  float s = 0.f;
#pragma unroll
  for (int j = 0; j < 4; j++)
    s += __expf(v[j].x - m) + __expf(v[j].y - m) +
         __expf(v[j].z - m) + __expf(v[j].w - m);
#pragma unroll
  for (int off = 32; off; off >>= 1) s += __shfl_xor(s, off);
  float conf = m + __logf(s);
  const float4* fp = (const float4*)(feas + (size_t)row * DDIM);
  float4 w[3];
  float ss = 0.f;
#pragma unroll
  for (int j = 0; j < 3; j++) {
    w[j] = fp[lane + j * 64];
    ss += w[j].x * w[j].x + w[j].y * w[j].y + w[j].z * w[j].z + w[j].w * w[j].w;
  }
#pragma unroll
  for (int off = 32; off; off >>= 1) ss += __shfl_xor(ss, off);
  float scale = conf / sqrtf(ss);
#pragma unroll
  for (int j = 0; j < 3; j++)
    dst[lane + j * 64] = make_ushort4(f2bf(w[j].x * scale), f2bf(w[j].y * scale),
                                      f2bf(w[j].z * scale), f2bf(w[j].w * scale));
}

// ---- row-wise logsumexp for logit -> energy ------------------------------
__global__ __launch_bounds__(256) void lse_rows(const float* __restrict__ x,
                                                float* __restrict__ out,
                                                int nrows, int ncols) {
  int row = blockIdx.x * 4 + (threadIdx.x >> 6);
  int lane = threadIdx.x & 63;
  if (row >= nrows) return;
  const float4* rp = (const float4*)(x + (size_t)row * ncols);
  int n4 = ncols >> 2;
  float4 v[4];
  float m = -3.0e38f;
#pragma unroll
  for (int j = 0; j < 4; j++) {
    int idx = lane + j * 64;
    if (idx < n4) {
      v[j] = rp[idx];
      m = fmaxf(m, fmaxf(fmaxf(v[j].x, v[j].y), fmaxf(v[j].z, v[j].w)));
    } else {
      v[j] = make_float4(-3.0e38f, -3.0e38f, -3.0e38f, -3.0e38f);
    }
  }
#pragma unroll
  for (int off = 32; off; off >>= 1) m = fmaxf(m, __shfl_xor(m, off));
  float s = 0.f;
#pragma unroll
  for (int j = 0; j < 4; j++)
    s += __expf(v[j].x - m) + __expf(v[j].y - m) +
         __expf(v[j].z - m) + __expf(v[j].w - m);
#pragma unroll
  for (int off = 32; off; off >>= 1) s += __shfl_xor(s, off);
  if (lane == 0) out[row] = m + __logf(s);
}

// ---- a16[q][d] = bf16(feature/||feature||) -------------------------------
__global__ __launch_bounds__(256) void feat_norm(const float* __restrict__ x,
                                                 ushort* __restrict__ y) {
  int row = blockIdx.x * 4 + (threadIdx.x >> 6);
  int lane = threadIdx.x & 63;
  if (row >= QROWS) return;
  const float4* rp = (const float4*)(x + (size_t)row * DDIM);
  float4 v[3];
  float ss = 0.f;
#pragma unroll
  for (int j = 0; j < 3; j++) {
    v[j] = rp[lane + j * 64];
    ss += v[j].x * v[j].x + v[j].y * v[j].y + v[j].z * v[j].z + v[j].w * v[j].w;
  }
#pragma unroll
  for (int off = 32; off; off >>= 1) ss += __shfl_xor(ss, off);
  float rn = 1.0f / sqrtf(ss);
  ushort4* dst = (ushort4*)(y + (size_t)row * DDIM);
#pragma unroll
  for (int j = 0; j < 3; j++)
    dst[lane + j * 64] = make_ushort4(f2bf(v[j].x * rn), f2bf(v[j].y * rn),
                                      f2bf(v[j].z * rn), f2bf(v[j].w * rn));
}

// ---- bf16 MFMA GEMM: 256x256 tile, 512 thr, 3-slot 32-K-subtile pipeline --
// counted vmcnt(4) (never 0 in steady state), raw s_barrier + sched_barrier,
// setprio around MFMA clusters. [256][32] LDS layout is bank-conflict-free.
#define GBM 256
#define GBN 256
#define KU  32
#define NU  (DDIM / KU)              // 24
#define GSLOT (GBM * KU)             // 8192 ushorts per operand slot
#define GNWG ((QROWS / GBM) * (NPAD / GBN))   // 16*400 = 6400

__device__ inline void load_lds16(const void* g, void* l) {
  __builtin_amdgcn_global_load_lds(
      (const __attribute__((address_space(1))) void*)g,
      (__attribute__((address_space(3))) void*)l, 16, 0, 0);
}

__global__ __launch_bounds__(512) void gemm_sims(const ushort* __restrict__ A,
                                                 const ushort* __restrict__ B,
                                                 ushort* __restrict__ C) {
  __shared__ ushort sA[3][GSLOT];
  __shared__ ushort sB[3][GSLOT];
  const int tid = threadIdx.x;
  const int lane = tid & 63;
  const int wm = (tid >> 6) >> 2;              // 0..1  (q half)
  const int wn = (tid >> 6) & 3;               // 0..3  (n quarter)
  const int lr = lane & 15, lg = lane >> 4;

  // XCD chunking (6400%8==0, bijective) + 4x4 supertiles (~3.1MB L2 ws)
  int flat = blockIdx.x;
  int wgid = (flat & 7) * (GNWG / 8) + (flat >> 3);
  int sup = wgid >> 4, wi = wgid & 15;
  int q_idx = (sup & 3) * 4 + (wi & 3);        // 0..15
  int n_idx = (sup >> 2) * 4 + (wi >> 2);      // 0..399
  const int qBase = q_idx * GBM;
  const int nBase = n_idx * GBN;

  floatx4 acc[8][4] = {};

  auto stageA = [&](int u, int slot) {         // 2 x global_load_lds / thread
#pragma unroll
    for (int r = 0; r < 2; r++) {
      int idx = r * 512 + tid;                 // 1024 x 16B = 256 rows x 64B
      load_lds16(A + (size_t)(qBase + (idx >> 2)) * DDIM + u * KU + (idx & 3) * 8,
                 &sA[slot][idx * 8]);
    }
  };
  auto stageB = [&](int u, int slot) {
#pragma unroll
    for (int r = 0; r < 2; r++) {
      int idx = r * 512 + tid;
      load_lds16(B + (size_t)(nBase + (idx >> 2)) * DDIM + u * KU + (idx & 3) * 8,
                 &sB[slot][idx * 8]);
    }
  };

  // prologue: stage units 0,1 (8 loads in flight per wave)
  stageA(0, 0); stageB(0, 0);
  stageA(1, 1); stageB(1, 1);

  for (int u = 0; u < NU; u++) {
    const int cur = u % 3;
    const bool stg = (u < NU - 2);
    if (u < NU - 1) {
      asm volatile("s_waitcnt vmcnt(4)" ::: "memory");   // unit u landed (own)
    } else {
      asm volatile("s_waitcnt vmcnt(0)" ::: "memory");   // last unit: drain
    }
    __builtin_amdgcn_s_barrier();              // all waves' portions landed
    __builtin_amdgcn_sched_barrier(0);
    const ushort* Ab = sA[cur];
    const ushort* Bb = sB[cur];

    // ---- phase 1: stage A(u+2) | ds_read B(all n) + A(m 0..3) | 16 MFMA ---
    if (stg) stageA(u + 2, (u + 2) % 3);
    bf16x8 bq[4], af[4];
#pragma unroll
    for (int n = 0; n < 4; n++)
      bq[n] = *(const bf16x8*)(Bb + (wn * 64 + n * 16 + lr) * KU + lg * 8);
#pragma unroll
    for (int m = 0; m < 4; m++)
      af[m] = *(const bf16x8*)(Ab + (wm * 128 + m * 16 + lr) * KU + lg * 8);
    __builtin_amdgcn_s_barrier();
    __builtin_amdgcn_sched_barrier(0);
    __builtin_amdgcn_s_setprio(1);
#pragma unroll
    for (int m = 0; m < 4; m++)
#pragma unroll
      for (int n = 0; n < 4; n++)
        acc[m][n] = __builtin_amdgcn_mfma_f32_16x16x32_bf16(af[m], bq[n],
                                                            acc[m][n], 0, 0, 0);
    __builtin_amdgcn_s_setprio(0);

    // ---- phase 2: stage B(u+2) | ds_read A(m 4..7) | 16 MFMA --------------
    if (stg) stageB(u + 2, (u + 2) % 3);
    bf16x8 ag[4];
#pragma unroll
    for (int m = 0; m < 4; m++)
      ag[m] = *(const bf16x8*)(Ab + (wm * 128 + 64 + m * 16 + lr) * KU + lg * 8);
    __builtin_amdgcn_s_barrier();
    __builtin_amdgcn_sched_barrier(0);
    __builtin_amdgcn_s_setprio(1);
#pragma unroll
    for (int m = 0; m < 4; m++)
#pragma unroll
      for (int n = 0; n < 4; n++)
        acc[m + 4][n] = __builtin_amdgcn_mfma_f32_16x16x32_bf16(ag[m], bq[n],
                                                                acc[m + 4][n], 0, 0, 0);
    __builtin_amdgcn_s_setprio(0);
  }

  // epilogue: C write (bf16)
#pragma unroll
  for (int m = 0; m < 8; m++)
#pragma unroll
    for (int n = 0; n < 4; n++) {
      int q = qBase + wm * 128 + m * 16 + lg * 4;
      int col = nBase + wn * 64 + n * 16 + lr;
      ushort* cp = C + (size_t)q * NPAD + col;
#pragma unroll
      for (int r = 0; r < 4; r++) cp[(size_t)r * NPAD] = f2bf(acc[m][n][r]);
    }
}

// ---- per-segment exact top-K multiset: 256 thr, 100 keys/thread in regs ---
// L = 100th-largest thread-max (<= T*); compact >=L to LDS; wave-independent
// barrier-free binary searches (all waves compute identical results).
__global__ __launch_bounds__(256) void topk_seg(const ushort* __restrict__ sims,
                                                ushort* __restrict__ cand) {
  __shared__ ushort smax[256];
  __shared__ ushort list[LCAP2];
  __shared__ int shC, shM, ipart[4];
  const int t = threadIdx.x;
  const int lane = t & 63;
  const int q = blockIdx.x >> 2, seg = blockIdx.x & 3;
  const uint2* base = (const uint2*)(sims + (size_t)q * NPAD + seg * SEGW);

  uint v[50];                                  // 100 ordered u16 keys
#pragma unroll
  for (int i = 0; i < 25; i++) {
    int jj = i * 256 + t;                      // uint2 index in segment
    uint2 w = base[jj];
    uint mm;
    mm = ((w.x >> 15) & 0x00010001u) * 0xffffu;
    v[2 * i]     = (w.x ^ mm) | (0x80008000u & ~mm);
    mm = ((w.y >> 15) & 0x00010001u) * 0xffffu;
    v[2 * i + 1] = (w.y ^ mm) | (0x80008000u & ~mm);
    if (seg == 3 && jj >= 5800) { v[2 * i] = 0; v[2 * i + 1] = 0; }  // pad cols
  }
  // thread max
  uint mx = 0;
#pragma unroll
  for (int i = 0; i < 50; i++) {
    uint a = v[i] & 0xffffu, b = v[i] >> 16;
    mx = a > mx ? a : mx;
    mx = b > mx ? b : mx;
  }
  smax[t] = (ushort)mx;
  if (t == 0) shC = 0;
  __syncthreads();

  // L = 100th largest of 256 thread maxima (wave-local, no barriers)
  uint m0 = smax[lane], m1 = smax[lane + 64], m2 = smax[lane + 128], m3 = smax[lane + 192];
  uint lo = 0, hi = 65536;
  while (hi - lo > 1) {
    uint mid = (lo + hi) >> 1;
    int c = (m0 >= mid) + (m1 >= mid) + (m2 >= mid) + (m3 >= mid);
#pragma unroll
    for (int off = 32; off; off >>= 1) c += __shfl_xor(c, off);
    if (c >= KTOP) lo = mid; else hi = mid;
  }
  const uint L = lo;

  // compact keys >= L into LDS
#pragma unroll
  for (int i = 0; i < 50; i++) {
    uint a = v[i] & 0xffffu, b = v[i] >> 16;
    if (a >= L) { int p = atomicAdd(&shC, 1); if (p < LCAP2) list[p] = (ushort)a; }
    if (b >= L) { int p = atomicAdd(&shC, 1); if (p < LCAP2) list[p] = (ushort)b; }
  }
  __syncthreads();
  const int C = shC;

  uint Tkey;
  if (C <= LCAP2) {                            // common path: search LDS list
    uint lo2 = L, hi2 = 65536;
    while (hi2 - lo2 > 1) {
      uint mid = (lo2 + hi2) >> 1;
      int c = 0;
      for (int i = lane; i < C; i += 64) c += ((uint)list[i] >= mid) ? 1 : 0;
#pragma unroll
      for (int off = 32; off; off >>= 1) c += __shfl_xor(c, off);
      if (c >= KTOP) lo2 = mid; else hi2 = mid;
    }
    Tkey = lo2;
  } else {                                     // rare fallback: regs + barriers
    uint lo2 = L, hi2 = 65536;
    while (hi2 - lo2 > 1) {
      uint mid = (lo2 + hi2) >> 1;
      int c = 0;
#pragma unroll
      for (int i = 0; i < 50; i++) {
        c += ((v[i] & 0xffffu) >= mid) ? 1 : 0;
        c += ((v[i] >> 16) >= mid) ? 1 : 0;
      }
#pragma unroll
      for (int off = 32; off; off >>= 1) c += __shfl_xor(c, off);
      __syncthreads();
      if (lane == 0) ipart[t >> 6] = c;
      __syncthreads();
      c = ipart[0] + ipart[1] + ipart[2] + ipart[3];
      if (c >= KTOP) lo2 = mid; else hi2 = mid;
    }
    Tkey = lo2;
  }

  // emit segment top-100 multiset: keys > T* (m<=99) + (100-m) copies of T*
  if (t == 0) shM = 0;
  __syncthreads();
  ushort* dst = cand + (size_t)q * 512 + seg * 128;
  if (C <= LCAP2) {
    for (int i = t; i < C; i += 256) {
      uint u = list[i];
      if (u > Tkey) { int p = atomicAdd(&shM, 1); dst[p] = (ushort)u; }
    }
  } else {
#pragma unroll
    for (int i = 0; i < 50; i++) {
      uint a = v[i] & 0xffffu, b = v[i] >> 16;
      if (a > Tkey) { int p = atomicAdd(&shM, 1); dst[p] = (ushort)a; }
      if (b > Tkey) { int p = atomicAdd(&shM, 1); dst[p] = (ushort)b; }
    }
  }
  __syncthreads();
  for (int i = shM + t; i < KTOP; i += 256) dst[i] = (ushort)Tkey;
}

// ---- merge 4x100 candidates + mean + energy -> out (1 wave / row) --------
__global__ __launch_bounds__(64) void topk_fin(const ushort* __restrict__ cand,
                                               const float* __restrict__ energy,
                                               float* __restrict__ out) {
  const int q = blockIdx.x;
  const int lane = threadIdx.x;
  const ushort* row = cand + (size_t)q * 512;
  ushort kk[8];
#pragma unroll
  for (int s = 0; s < 4; s++) {
    kk[2 * s]     = (lane < KTOP) ? row[s * 128 + lane] : (ushort)0;
    kk[2 * s + 1] = (lane + 64 < KTOP) ? row[s * 128 + 64 + lane] : (ushort)0;
  }
  uint lo = 0, hi = 65536;
  while (hi - lo > 1) {
    uint mid = (lo + hi) >> 1;
    int c = 0;
#pragma unroll
    for (int i = 0; i < 8; i++) c += ((uint)kk[i] >= mid) ? 1 : 0;
#pragma unroll
    for (int off = 32; off; off >>= 1) c += __shfl_xor(c, off);
    if (c >= KTOP) lo = mid; else hi = mid;
  }
  const uint T = lo;
  float s = 0.f;
  int m = 0;
#pragma unroll
  for (int i = 0; i < 8; i++) {
    if ((uint)kk[i] > T) { s += o16f(kk[i]); m++; }
  }
#pragma unroll
  for (int off = 32; off; off >>= 1) {
    s += __shfl_xor(s, off);
    m += __shfl_xor(m, off);
  }
  if (lane == 0) {
    float total = s + (float)(KTOP - m) * o16f((ushort)T);
    out[q] = -(total * (1.0f / KTOP)) * energy[q];
  }
}

extern "C" void kernel_launch(void* const* d_in, const int* in_sizes, int n_in,
                              void* d_out, int out_size, void* d_ws, size_t ws_size,
                              hipStream_t stream) {
  const float* feature     = (const float*)d_in[0];
  const float* logit       = (const float*)d_in[1];
  const float* bank_feas   = (const float*)d_in[2];
  const float* bank_logits = (const float*)d_in[3];
  // d_in[4] is K (device scalar) — problem instance fixes K = 100 (KTOP).
  float* out = (float*)d_out;

  char* ws = (char*)d_ws;
  size_t off = 0;
  auto take = [&](size_t bytes) -> char* {
    char* p = ws + off;
    off = (off + bytes + 255) & ~(size_t)255;
    return p;
  };
  float*  energy = (float*)take((size_t)QROWS * 4);
  ushort* a16    = (ushort*)take((size_t)QROWS * DDIM * 2);
  ushort* b16    = (ushort*)take((size_t)NPAD * DDIM * 2);
  ushort* sims   = (ushort*)take((size_t)QROWS * NPAD * 2);
  ushort* cand   = (ushort*)take((size_t)QROWS * 512 * 2);
  if (off > ws_size) return;  // needs ~1.01 GB

  bank_prep<<<dim3(NPAD / 4), dim3(256), 0, stream>>>(bank_logits, bank_feas, b16);
  lse_rows <<<dim3(QROWS / 4), dim3(256), 0, stream>>>(logit, energy, QROWS, CDIM);
  feat_norm<<<dim3(QROWS / 4), dim3(256), 0, stream>>>(feature, a16);
  gemm_sims<<<dim3(GNWG), dim3(512), 0, stream>>>(a16, b16, sims);
  topk_seg <<<dim3(QROWS * 4), dim3(256), 0, stream>>>(sims, cand);
  topk_fin <<<dim3(QROWS), dim3(64), 0, stream>>>(cand, energy, out);
}

// Round 5
// 1460.822 us; speedup vs baseline: 2.0481x; 1.1944x over previous
//
#include <hip/hip_runtime.h>
#include <hip/hip_bf16.h>

#define QROWS 4096
#define DDIM  768
#define NBANK 100000
#define CDIM  1000
#define KTOP  100
#define NPAD  102400                 // padded bank cols
#define SEGW2 12800                  // NPAD/8 keys per top-k segment
#define LCAP2 4096                   // LDS candidate cap in topk_seg

typedef float floatx4 __attribute__((ext_vector_type(4)));
typedef short bf16x8 __attribute__((ext_vector_type(8)));

__device__ inline ushort f2bf(float f) {            // f32 -> bf16 RNE
  uint b = __float_as_uint(f);
  uint r = b + 0x7fffu + ((b >> 16) & 1u);
  return (ushort)(r >> 16);
}
__device__ inline float o16f(ushort u) {            // ordered u16 -> f32 value
  ushort b = (u & 0x8000) ? (ushort)(u & 0x7fff) : (ushort)~u;
  return __uint_as_float((uint)b << 16);
}

// ---- bank_prep: conf=LSE(logits), b16[row]=bf16(feas*conf/||feas||) ------
__global__ __launch_bounds__(256) void bank_prep(const float* __restrict__ logits,
                                                 const float* __restrict__ feas,
                                                 ushort* __restrict__ b16) {
  int row = blockIdx.x * 4 + (threadIdx.x >> 6);
  int lane = threadIdx.x & 63;
  if (row >= NPAD) return;
  ushort4* dst = (ushort4*)(b16 + (size_t)row * DDIM);
  if (row >= NBANK) {
#pragma unroll
    for (int j = 0; j < 3; j++) dst[lane + j * 64] = make_ushort4(0, 0, 0, 0);
    return;
  }
  const float4* lp = (const float4*)(logits + (size_t)row * CDIM);
  float4 v[4];
  float m = -3.0e38f;
#pragma unroll
  for (int j = 0; j < 4; j++) {
    int idx = lane + j * 64;
    if (idx < CDIM / 4) {
      v[j] = lp[idx];
      m = fmaxf(m, fmaxf(fmaxf(v[j].x, v[j].y), fmaxf(v[j].z, v[j].w)));
    } else {
      v[j] = make_float4(-3.0e38f, -3.0e38f, -3.0e38f, -3.0e38f);
    }
  }
#pragma unroll
  for (int off = 32; off; off >>= 1) m = fmaxf(m, __shfl_xor(m, off));
  float s = 0.f;
#pragma unroll
  for (int j = 0; j < 4; j++)
    s += __expf(v[j].x - m) + __expf(v[j].y - m) +
         __expf(v[j].z - m) + __expf(v[j].w - m);
#pragma unroll
  for (int off = 32; off; off >>= 1) s += __shfl_xor(s, off);
  float conf = m + __logf(s);
  const float4* fp = (const float4*)(feas + (size_t)row * DDIM);
  float4 w[3];
  float ss = 0.f;
#pragma unroll
  for (int j = 0; j < 3; j++) {
    w[j] = fp[lane + j * 64];
    ss += w[j].x * w[j].x + w[j].y * w[j].y + w[j].z * w[j].z + w[j].w * w[j].w;
  }
#pragma unroll
  for (int off = 32; off; off >>= 1) ss += __shfl_xor(ss, off);
  float scale = conf / sqrtf(ss);
#pragma unroll
  for (int j = 0; j < 3; j++)
    dst[lane + j * 64] = make_ushort4(f2bf(w[j].x * scale), f2bf(w[j].y * scale),
                                      f2bf(w[j].z * scale), f2bf(w[j].w * scale));
}

// ---- row-wise logsumexp for logit -> energy ------------------------------
__global__ __launch_bounds__(256) void lse_rows(const float* __restrict__ x,
                                                float* __restrict__ out,
                                                int nrows, int ncols) {
  int row = blockIdx.x * 4 + (threadIdx.x >> 6);
  int lane = threadIdx.x & 63;
  if (row >= nrows) return;
  const float4* rp = (const float4*)(x + (size_t)row * ncols);
  int n4 = ncols >> 2;
  float4 v[4];
  float m = -3.0e38f;
#pragma unroll
  for (int j = 0; j < 4; j++) {
    int idx = lane + j * 64;
    if (idx < n4) {
      v[j] = rp[idx];
      m = fmaxf(m, fmaxf(fmaxf(v[j].x, v[j].y), fmaxf(v[j].z, v[j].w)));
    } else {
      v[j] = make_float4(-3.0e38f, -3.0e38f, -3.0e38f, -3.0e38f);
    }
  }
#pragma unroll
  for (int off = 32; off; off >>= 1) m = fmaxf(m, __shfl_xor(m, off));
  float s = 0.f;
#pragma unroll
  for (int j = 0; j < 4; j++)
    s += __expf(v[j].x - m) + __expf(v[j].y - m) +
         __expf(v[j].z - m) + __expf(v[j].w - m);
#pragma unroll
  for (int off = 32; off; off >>= 1) s += __shfl_xor(s, off);
  if (lane == 0) out[row] = m + __logf(s);
}

// ---- a16[q][d] = bf16(feature/||feature||) -------------------------------
__global__ __launch_bounds__(256) void feat_norm(const float* __restrict__ x,
                                                 ushort* __restrict__ y) {
  int row = blockIdx.x * 4 + (threadIdx.x >> 6);
  int lane = threadIdx.x & 63;
  if (row >= QROWS) return;
  const float4* rp = (const float4*)(x + (size_t)row * DDIM);
  float4 v[3];
  float ss = 0.f;
#pragma unroll
  for (int j = 0; j < 3; j++) {
    v[j] = rp[lane + j * 64];
    ss += v[j].x * v[j].x + v[j].y * v[j].y + v[j].z * v[j].z + v[j].w * v[j].w;
  }
#pragma unroll
  for (int off = 32; off; off >>= 1) ss += __shfl_xor(ss, off);
  float rn = 1.0f / sqrtf(ss);
  ushort4* dst = (ushort4*)(y + (size_t)row * DDIM);
#pragma unroll
  for (int j = 0; j < 3; j++)
    dst[lane + j * 64] = make_ushort4(f2bf(v[j].x * rn), f2bf(v[j].y * rn),
                                      f2bf(v[j].z * rn), f2bf(v[j].w * rn));
}

// ---- bf16 MFMA GEMM v3: 256x128 tile, BK=64, 3-slot pipeline, st_16x32 ----
// swizzle (pre-swizzled global source + swizzled ds_read), counted vmcnt(6),
// one barrier per K-tile, setprio around MFMA clusters.
#define GBM 256
#define GBN 128
#define GBK 64
#define NT  (DDIM / GBK)                       // 12 K-tiles
#define SLOTU 24576                            // ushorts per slot (A 16384 + B 8192)
#define GNWG ((QROWS / GBM) * (NPAD / GBN))    // 16*800 = 12800

__device__ inline void load_lds16(const void* g, void* l) {
  __builtin_amdgcn_global_load_lds(
      (const __attribute__((address_space(1))) void*)g,
      (__attribute__((address_space(3))) void*)l, 16, 0, 0);
}

__global__ __launch_bounds__(512) void gemm_sims(const ushort* __restrict__ A,
                                                 const ushort* __restrict__ B,
                                                 ushort* __restrict__ C) {
  __shared__ ushort lds[3 * SLOTU];            // 144 KB
  const int tid = threadIdx.x;
  const int lane = tid & 63;
  const int wid = tid >> 6;
  const int wm = wid >> 1, wn = wid & 1;       // 4x2 waves, each 64x64 out
  const int lr = lane & 15, lg = lane >> 4;

  // XCD chunking (12800%8==0, bijective) + 4x4 supertiles (~2.3MB L2 ws)
  int flat = blockIdx.x;
  int wgid = (flat & 7) * (GNWG / 8) + (flat >> 3);
  int sup = wgid >> 4, wi = wgid & 15;
  int q_idx = (sup & 3) * 4 + (wi & 3);        // 0..15
  int n_idx = (sup >> 2) * 4 + (wi >> 2);      // 0..799
  const int qBase = q_idx * GBM;
  const int nBase = n_idx * GBN;

  // staging lane geometry (st_16x32: physical colb = logical colb ^ ((row>>2&1)<<5))
  const int rin = lane >> 3;                   // row within 8-row group
  const int sub = lane & 7;                    // 16B chunk within 128B row
  const int csw = (sub * 16) ^ (((lane >> 5) & 1) << 5);  // swizzled source byte col

  auto stage = [&](int t, int slot, int rlo, int rhi) {
    for (int r = rlo; r < rhi; r++) {
      int G = r * 8 + wid;                     // 0..47 (uniform per wave)
      if (G < 32) {                            // A group: rows qBase+G*8..+8
        int row = qBase + G * 8 + rin;
        load_lds16(A + (size_t)row * DDIM + t * GBK + (csw >> 1),
                   lds + slot * SLOTU + G * 512 + lane * 8);
      } else {                                 // B group
        int row = nBase + (G - 32) * 8 + rin;
        load_lds16(B + (size_t)row * DDIM + t * GBK + (csw >> 1),
                   lds + slot * SLOTU + 16384 + (G - 32) * 512 + lane * 8);
      }
    }
  };

  floatx4 acc[4][4] = {};
  const int swr = ((lr >> 2) & 1) << 5;        // read-side byte xor

  stage(0, 0, 0, 6);
  stage(1, 1, 0, 6);

  for (int t = 0; t < NT; t++) {
    const int cs = t % 3;
    if (t < NT - 1) {
      asm volatile("s_waitcnt vmcnt(6)" ::: "memory");
    } else {
      asm volatile("s_waitcnt vmcnt(0)" ::: "memory");
    }
    __builtin_amdgcn_s_barrier();
    __builtin_amdgcn_sched_barrier(0);
    const ushort* Ab = lds + cs * SLOTU;
    const ushort* Bb = lds + cs * SLOTU + 16384;

#pragma unroll
    for (int kk = 0; kk < 2; kk++) {
      if (t < NT - 2) stage(t + 2, (t + 2) % 3, kk * 3, kk * 3 + 3);
      const int koffu = ((kk * 64 + lg * 16) ^ swr) >> 1;   // ushort offset in row
      bf16x8 af[4], bf[4];
#pragma unroll
      for (int m = 0; m < 4; m++)
        af[m] = *(const bf16x8*)(Ab + (wm * 64 + m * 16 + lr) * 64 + koffu);
#pragma unroll
      for (int n = 0; n < 4; n++)
        bf[n] = *(const bf16x8*)(Bb + (wn * 64 + n * 16 + lr) * 64 + koffu);
      __builtin_amdgcn_s_setprio(1);
#pragma unroll
      for (int m = 0; m < 4; m++)
#pragma unroll
        for (int n = 0; n < 4; n++)
          acc[m][n] = __builtin_amdgcn_mfma_f32_16x16x32_bf16(af[m], bf[n],
                                                              acc[m][n], 0, 0, 0);
      __builtin_amdgcn_s_setprio(0);
    }
  }

  // epilogue: C write (bf16)
#pragma unroll
  for (int m = 0; m < 4; m++)
#pragma unroll
    for (int n = 0; n < 4; n++) {
      int q = qBase + wm * 64 + m * 16 + lg * 4;
      int col = nBase + wn * 64 + n * 16 + lr;
      ushort* cp = C + (size_t)q * NPAD + col;
#pragma unroll
      for (int r = 0; r < 4; r++) cp[(size_t)r * NPAD] = f2bf(acc[m][n][r]);
    }
}

// ---- per-segment exact top-K multiset: 256 thr, 50 keys/thread in regs ----
__global__ __launch_bounds__(256) void topk_seg(const ushort* __restrict__ sims,
                                                ushort* __restrict__ cand) {
  __shared__ ushort smax[256];
  __shared__ ushort list[LCAP2];
  __shared__ int shC, shM, ipart[4];
  const int t = threadIdx.x;
  const int lane = t & 63;
  const int q = blockIdx.x >> 3, seg = blockIdx.x & 7;
  const ushort* base = sims + (size_t)q * NPAD + seg * SEGW2;

  uint v[25];                                  // 50 ordered u16 keys
#pragma unroll
  for (int i = 0; i < 6; i++) {                // 6 x uint4 = 48 keys
    uint4 w = ((const uint4*)base)[i * 256 + t];
    uint ww[4] = {w.x, w.y, w.z, w.w};
#pragma unroll
    for (int e = 0; e < 4; e++) {
      uint u = ww[e];
      uint mm = ((u >> 15) & 0x00010001u) * 0xffffu;
      v[4 * i + e] = (u ^ mm) | (0x80008000u & ~mm);
    }
    if (seg == 7 && (i * 256 + t) >= 1300) {   // pad cols >= 100000
      v[4 * i] = 0; v[4 * i + 1] = 0; v[4 * i + 2] = 0; v[4 * i + 3] = 0;
    }
  }
  {                                            // tail: 2 keys (never valid in seg 7)
    if (seg == 7) {
      v[24] = 0;
    } else {
      uint u = ((const uint*)base)[6144 + t];
      uint mm = ((u >> 15) & 0x00010001u) * 0xffffu;
      v[24] = (u ^ mm) | (0x80008000u & ~mm);
    }
  }
  // thread max
  uint mx = 0;
#pragma unroll
  for (int i = 0; i < 25; i++) {
    uint a = v[i] & 0xffffu, b = v[i] >> 16;
    mx = a > mx ? a : mx;
    mx = b > mx ? b : mx;
  }
  smax[t] = (ushort)mx;
  if (t == 0) shC = 0;
  __syncthreads();

  // L = 100th largest of 256 thread maxima (wave-local, no barriers)
  uint m0 = smax[lane], m1 = smax[lane + 64], m2 = smax[lane + 128], m3 = smax[lane + 192];
  uint lo = 0, hi = 65536;
  while (hi - lo > 1) {
    uint mid = (lo + hi) >> 1;
    int c = (m0 >= mid) + (m1 >= mid) + (m2 >= mid) + (m3 >= mid);
#pragma unroll
    for (int off = 32; off; off >>= 1) c += __shfl_xor(c, off);
    if (c >= KTOP) lo = mid; else hi = mid;
  }
  const uint L = lo;

  // compact keys >= L into LDS
#pragma unroll
  for (int i = 0; i < 25; i++) {
    uint a = v[i] & 0xffffu, b = v[i] >> 16;
    if (a >= L) { int p = atomicAdd(&shC, 1); if (p < LCAP2) list[p] = (ushort)a; }
    if (b >= L) { int p = atomicAdd(&shC, 1); if (p < LCAP2) list[p] = (ushort)b; }
  }
  __syncthreads();
  const int C = shC;

  uint Tkey;
  if (C <= LCAP2) {                            // common path: search LDS list
    uint lo2 = L, hi2 = 65536;
    while (hi2 - lo2 > 1) {
      uint mid = (lo2 + hi2) >> 1;
      int c = 0;
      for (int i = lane; i < C; i += 64) c += ((uint)list[i] >= mid) ? 1 : 0;
#pragma unroll
      for (int off = 32; off; off >>= 1) c += __shfl_xor(c, off);
      if (c >= KTOP) lo2 = mid; else hi2 = mid;
    }
    Tkey = lo2;
  } else {                                     // rare fallback: regs + barriers
    uint lo2 = L, hi2 = 65536;
    while (hi2 - lo2 > 1) {
      uint mid = (lo2 + hi2) >> 1;
      int c = 0;
#pragma unroll
      for (int i = 0; i < 25; i++) {
        c += ((v[i] & 0xffffu) >= mid) ? 1 : 0;
        c += ((v[i] >> 16) >= mid) ? 1 : 0;
      }
#pragma unroll
      for (int off = 32; off; off >>= 1) c += __shfl_xor(c, off);
      __syncthreads();
      if (lane == 0) ipart[t >> 6] = c;
      __syncthreads();
      c = ipart[0] + ipart[1] + ipart[2] + ipart[3];
      if (c >= KTOP) lo2 = mid; else hi2 = mid;
    }
    Tkey = lo2;
  }

  // emit segment top-100 multiset
  if (t == 0) shM = 0;
  __syncthreads();
  ushort* dst = cand + (size_t)q * 1024 + seg * 128;
  if (C <= LCAP2) {
    for (int i = t; i < C; i += 256) {
      uint u = list[i];
      if (u > Tkey) { int p = atomicAdd(&shM, 1); dst[p] = (ushort)u; }
    }
  } else {
#pragma unroll
    for (int i = 0; i < 25; i++) {
      uint a = v[i] & 0xffffu, b = v[i] >> 16;
      if (a > Tkey) { int p = atomicAdd(&shM, 1); dst[p] = (ushort)a; }
      if (b > Tkey) { int p = atomicAdd(&shM, 1); dst[p] = (ushort)b; }
    }
  }
  __syncthreads();
  for (int i = shM + t; i < KTOP; i += 256) dst[i] = (ushort)Tkey;
}

// ---- merge 8x100 candidates + mean + energy -> out (1 wave / row) --------
__global__ __launch_bounds__(64) void topk_fin(const ushort* __restrict__ cand,
                                               const float* __restrict__ energy,
                                               float* __restrict__ out) {
  const int q = blockIdx.x;
  const int t = threadIdx.x;
  const ushort* row = cand + (size_t)q * 1024;
  ushort kk[16];
#pragma unroll
  for (int s = 0; s < 8; s++) {
    kk[2 * s]     = row[s * 128 + t];                                  // t < 100
    kk[2 * s + 1] = (t + 64 < KTOP) ? row[s * 128 + 64 + t] : (ushort)0;
  }
  uint lo = 0, hi = 65536;
  while (hi - lo > 1) {
    uint mid = (lo + hi) >> 1;
    int c = 0;
#pragma unroll
    for (int i = 0; i < 16; i++) c += ((uint)kk[i] >= mid) ? 1 : 0;
#pragma unroll
    for (int off = 32; off; off >>= 1) c += __shfl_xor(c, off);
    if (c >= KTOP) lo = mid; else hi = mid;
  }
  const uint T = lo;
  float s = 0.f;
  int m = 0;
#pragma unroll
  for (int i = 0; i < 16; i++) {
    if ((uint)kk[i] > T) { s += o16f(kk[i]); m++; }
  }
#pragma unroll
  for (int off = 32; off; off >>= 1) {
    s += __shfl_xor(s, off);
    m += __shfl_xor(m, off);
  }
  if (t == 0) {
    float total = s + (float)(KTOP - m) * o16f((ushort)T);
    out[q] = -(total * (1.0f / KTOP)) * energy[q];
  }
}

extern "C" void kernel_launch(void* const* d_in, const int* in_sizes, int n_in,
                              void* d_out, int out_size, void* d_ws, size_t ws_size,
                              hipStream_t stream) {
  const float* feature     = (const float*)d_in[0];
  const float* logit       = (const float*)d_in[1];
  const float* bank_feas   = (const float*)d_in[2];
  const float* bank_logits = (const float*)d_in[3];
  // d_in[4] is K (device scalar) — problem instance fixes K = 100 (KTOP).
  float* out = (float*)d_out;

  char* ws = (char*)d_ws;
  size_t off = 0;
  auto take = [&](size_t bytes) -> char* {
    char* p = ws + off;
    off = (off + bytes + 255) & ~(size_t)255;
    return p;
  };
  float*  energy = (float*)take((size_t)QROWS * 4);
  ushort* a16    = (ushort*)take((size_t)QROWS * DDIM * 2);
  ushort* b16    = (ushort*)take((size_t)NPAD * DDIM * 2);
  ushort* sims   = (ushort*)take((size_t)QROWS * NPAD * 2);
  ushort* cand   = (ushort*)take((size_t)QROWS * 1024 * 2);
  if (off > ws_size) return;  // needs ~1.02 GB

  bank_prep<<<dim3(NPAD / 4), dim3(256), 0, stream>>>(bank_logits, bank_feas, b16);
  lse_rows <<<dim3(QROWS / 4), dim3(256), 0, stream>>>(logit, energy, QROWS, CDIM);
  feat_norm<<<dim3(QROWS / 4), dim3(256), 0, stream>>>(feature, a16);
  gemm_sims<<<dim3(GNWG), dim3(512), 0, stream>>>(a16, b16, sims);
  topk_seg <<<dim3(QROWS * 8), dim3(256), 0, stream>>>(sims, cand);
  topk_fin <<<dim3(QROWS), dim3(64), 0, stream>>>(cand, energy, out);
}

// Round 6
// 1454.248 us; speedup vs baseline: 2.0574x; 1.0045x over previous
//
#include <hip/hip_runtime.h>
#include <hip/hip_bf16.h>

#define QROWS 4096
#define DDIM  768
#define NBANK 100000
#define CDIM  1000
#define KTOP  100
#define NPAD  102400                 // padded bank cols
#define SEGW2 12800                  // NPAD/8 keys per top-k segment
#define LCAP2 4096                   // LDS candidate cap in topk_seg

typedef float floatx4 __attribute__((ext_vector_type(4)));
typedef short bf16x8 __attribute__((ext_vector_type(8)));

__device__ inline ushort f2bf(float f) {            // f32 -> bf16 RNE
  uint b = __float_as_uint(f);
  uint r = b + 0x7fffu + ((b >> 16) & 1u);
  return (ushort)(r >> 16);
}
__device__ inline float o16f(ushort u) {            // ordered u16 -> f32 value
  ushort b = (u & 0x8000) ? (ushort)(u & 0x7fff) : (ushort)~u;
  return __uint_as_float((uint)b << 16);
}

// ---- bank_prep: conf=LSE(logits), b16[row]=bf16(feas*conf/||feas||) ------
__global__ __launch_bounds__(256) void bank_prep(const float* __restrict__ logits,
                                                 const float* __restrict__ feas,
                                                 ushort* __restrict__ b16) {
  int row = blockIdx.x * 4 + (threadIdx.x >> 6);
  int lane = threadIdx.x & 63;
  if (row >= NPAD) return;
  ushort4* dst = (ushort4*)(b16 + (size_t)row * DDIM);
  if (row >= NBANK) {
#pragma unroll
    for (int j = 0; j < 3; j++) dst[lane + j * 64] = make_ushort4(0, 0, 0, 0);
    return;
  }
  const float4* lp = (const float4*)(logits + (size_t)row * CDIM);
  float4 v[4];
  float m = -3.0e38f;
#pragma unroll
  for (int j = 0; j < 4; j++) {
    int idx = lane + j * 64;
    if (idx < CDIM / 4) {
      v[j] = lp[idx];
      m = fmaxf(m, fmaxf(fmaxf(v[j].x, v[j].y), fmaxf(v[j].z, v[j].w)));
    } else {
      v[j] = make_float4(-3.0e38f, -3.0e38f, -3.0e38f, -3.0e38f);
    }
  }
#pragma unroll
  for (int off = 32; off; off >>= 1) m = fmaxf(m, __shfl_xor(m, off));
  float s = 0.f;
#pragma unroll
  for (int j = 0; j < 4; j++)
    s += __expf(v[j].x - m) + __expf(v[j].y - m) +
         __expf(v[j].z - m) + __expf(v[j].w - m);
#pragma unroll
  for (int off = 32; off; off >>= 1) s += __shfl_xor(s, off);
  float conf = m + __logf(s);
  const float4* fp = (const float4*)(feas + (size_t)row * DDIM);
  float4 w[3];
  float ss = 0.f;
#pragma unroll
  for (int j = 0; j < 3; j++) {
    w[j] = fp[lane + j * 64];
    ss += w[j].x * w[j].x + w[j].y * w[j].y + w[j].z * w[j].z + w[j].w * w[j].w;
  }
#pragma unroll
  for (int off = 32; off; off >>= 1) ss += __shfl_xor(ss, off);
  float scale = conf / sqrtf(ss);
#pragma unroll
  for (int j = 0; j < 3; j++)
    dst[lane + j * 64] = make_ushort4(f2bf(w[j].x * scale), f2bf(w[j].y * scale),
                                      f2bf(w[j].z * scale), f2bf(w[j].w * scale));
}

// ---- row-wise logsumexp for logit -> energy ------------------------------
__global__ __launch_bounds__(256) void lse_rows(const float* __restrict__ x,
                                                float* __restrict__ out,
                                                int nrows, int ncols) {
  int row = blockIdx.x * 4 + (threadIdx.x >> 6);
  int lane = threadIdx.x & 63;
  if (row >= nrows) return;
  const float4* rp = (const float4*)(x + (size_t)row * ncols);
  int n4 = ncols >> 2;
  float4 v[4];
  float m = -3.0e38f;
#pragma unroll
  for (int j = 0; j < 4; j++) {
    int idx = lane + j * 64;
    if (idx < n4) {
      v[j] = rp[idx];
      m = fmaxf(m, fmaxf(fmaxf(v[j].x, v[j].y), fmaxf(v[j].z, v[j].w)));
    } else {
      v[j] = make_float4(-3.0e38f, -3.0e38f, -3.0e38f, -3.0e38f);
    }
  }
#pragma unroll
  for (int off = 32; off; off >>= 1) m = fmaxf(m, __shfl_xor(m, off));
  float s = 0.f;
#pragma unroll
  for (int j = 0; j < 4; j++)
    s += __expf(v[j].x - m) + __expf(v[j].y - m) +
         __expf(v[j].z - m) + __expf(v[j].w - m);
#pragma unroll
  for (int off = 32; off; off >>= 1) s += __shfl_xor(s, off);
  if (lane == 0) out[row] = m + __logf(s);
}

// ---- a16[q][d] = bf16(feature/||feature||) -------------------------------
__global__ __launch_bounds__(256) void feat_norm(const float* __restrict__ x,
                                                 ushort* __restrict__ y) {
  int row = blockIdx.x * 4 + (threadIdx.x >> 6);
  int lane = threadIdx.x & 63;
  if (row >= QROWS) return;
  const float4* rp = (const float4*)(x + (size_t)row * DDIM);
  float4 v[3];
  float ss = 0.f;
#pragma unroll
  for (int j = 0; j < 3; j++) {
    v[j] = rp[lane + j * 64];
    ss += v[j].x * v[j].x + v[j].y * v[j].y + v[j].z * v[j].z + v[j].w * v[j].w;
  }
#pragma unroll
  for (int off = 32; off; off >>= 1) ss += __shfl_xor(ss, off);
  float rn = 1.0f / sqrtf(ss);
  ushort4* dst = (ushort4*)(y + (size_t)row * DDIM);
#pragma unroll
  for (int j = 0; j < 3; j++)
    dst[lane + j * 64] = make_ushort4(f2bf(v[j].x * rn), f2bf(v[j].y * rn),
                                      f2bf(v[j].z * rn), f2bf(v[j].w * rn));
}

// ---- bf16 MFMA GEMM v4: 256x128 tile, BK=64, 3-slot pipeline --------------
// 3-bit XOR swizzle (G4 recipe): phys_byte_col = col ^ ((row&7)<<4), applied
// as pre-swizzled GLOBAL source (LDS dest linear, rule #21) + swizzled
// ds_read. 16 frag-read lanes spread over all 8 16B-slots = 2-way = free.
// Counted vmcnt(6), one barrier per K-tile, setprio around MFMA clusters.
#define GBM 256
#define GBN 128
#define GBK 64
#define NT  (DDIM / GBK)                       // 12 K-tiles
#define SLOTU 24576                            // ushorts per slot (A 16384 + B 8192)
#define GNWG ((QROWS / GBM) * (NPAD / GBN))    // 16*800 = 12800

__device__ inline void load_lds16(const void* g, void* l) {
  __builtin_amdgcn_global_load_lds(
      (const __attribute__((address_space(1))) void*)g,
      (__attribute__((address_space(3))) void*)l, 16, 0, 0);
}

__global__ __launch_bounds__(512) void gemm_sims(const ushort* __restrict__ A,
                                                 const ushort* __restrict__ B,
                                                 ushort* __restrict__ C) {
  __shared__ ushort lds[3 * SLOTU];            // 144 KB
  const int tid = threadIdx.x;
  const int lane = tid & 63;
  const int wid = tid >> 6;
  const int wm = wid >> 1, wn = wid & 1;       // 4x2 waves, each 64x64 out
  const int lr = lane & 15, lg = lane >> 4;

  // XCD chunking (12800%8==0, bijective) + 4x4 supertiles (~2.3MB L2 ws)
  int flat = blockIdx.x;
  int wgid = (flat & 7) * (GNWG / 8) + (flat >> 3);
  int sup = wgid >> 4, wi = wgid & 15;
  int q_idx = (sup & 3) * 4 + (wi & 3);        // 0..15
  int n_idx = (sup >> 2) * 4 + (wi >> 2);      // 0..799
  const int qBase = q_idx * GBM;
  const int nBase = n_idx * GBN;

  // staging lane geometry: row-in-group rin = lane>>3, 16B slot sub = lane&7.
  // LDS dest is linear (slot sub); source column = logical slot sub^rin
  // (inverse of phys = logical ^ (row&7), row&7 == rin).
  const int rin = lane >> 3;
  const int csw = (((lane & 7) ^ rin) << 4);   // pre-swizzled source byte col

  auto stage = [&](int t, int slot, int rlo, int rhi) {
    for (int r = rlo; r < rhi; r++) {
      int G = r * 8 + wid;                     // 0..47 (uniform per wave)
      if (G < 32) {                            // A group: rows qBase+G*8..+8
        int row = qBase + G * 8 + rin;
        load_lds16(A + (size_t)row * DDIM + t * GBK + (csw >> 1),
                   lds + slot * SLOTU + G * 512 + lane * 8);
      } else {                                 // B group
        int row = nBase + (G - 32) * 8 + rin;
        load_lds16(B + (size_t)row * DDIM + t * GBK + (csw >> 1),
                   lds + slot * SLOTU + 16384 + (G - 32) * 512 + lane * 8);
      }
    }
  };

  floatx4 acc[4][4] = {};
  const int swr = (lr & 7) << 4;               // read-side byte xor

  stage(0, 0, 0, 6);
  stage(1, 1, 0, 6);

  for (int t = 0; t < NT; t++) {
    const int cs = t % 3;
    if (t < NT - 1) {
      asm volatile("s_waitcnt vmcnt(6)" ::: "memory");
    } else {
      asm volatile("s_waitcnt vmcnt(0)" ::: "memory");
    }
    __builtin_amdgcn_s_barrier();
    __builtin_amdgcn_sched_barrier(0);
    const ushort* Ab = lds + cs * SLOTU;
    const ushort* Bb = lds + cs * SLOTU + 16384;

#pragma unroll
    for (int kk = 0; kk < 2; kk++) {
      if (t < NT - 2) stage(t + 2, (t + 2) % 3, kk * 3, kk * 3 + 3);
      const int koffu = ((kk * 64 + lg * 16) ^ swr) >> 1;   // ushort offset in row
      bf16x8 af[4], bf[4];
#pragma unroll
      for (int m = 0; m < 4; m++)
        af[m] = *(const bf16x8*)(Ab + (wm * 64 + m * 16 + lr) * 64 + koffu);
#pragma unroll
      for (int n = 0; n < 4; n++)
        bf[n] = *(const bf16x8*)(Bb + (wn * 64 + n * 16 + lr) * 64 + koffu);
      __builtin_amdgcn_s_setprio(1);
#pragma unroll
      for (int m = 0; m < 4; m++)
#pragma unroll
        for (int n = 0; n < 4; n++)
          acc[m][n] = __builtin_amdgcn_mfma_f32_16x16x32_bf16(af[m], bf[n],
                                                              acc[m][n], 0, 0, 0);
      __builtin_amdgcn_s_setprio(0);
    }
  }

  // epilogue: C write (bf16)
#pragma unroll
  for (int m = 0; m < 4; m++)
#pragma unroll
    for (int n = 0; n < 4; n++) {
      int q = qBase + wm * 64 + m * 16 + lg * 4;
      int col = nBase + wn * 64 + n * 16 + lr;
      ushort* cp = C + (size_t)q * NPAD + col;
#pragma unroll
      for (int r = 0; r < 4; r++) cp[(size_t)r * NPAD] = f2bf(acc[m][n][r]);
    }
}

// ---- per-segment exact top-K multiset: 256 thr, 50 keys/thread in regs ----
__global__ __launch_bounds__(256) void topk_seg(const ushort* __restrict__ sims,
                                                ushort* __restrict__ cand) {
  __shared__ ushort smax[256];
  __shared__ ushort list[LCAP2];
  __shared__ int shC, shM, ipart[4];
  const int t = threadIdx.x;
  const int lane = t & 63;
  const int q = blockIdx.x >> 3, seg = blockIdx.x & 7;
  const ushort* base = sims + (size_t)q * NPAD + seg * SEGW2;

  uint v[25];                                  // 50 ordered u16 keys
#pragma unroll
  for (int i = 0; i < 6; i++) {                // 6 x uint4 = 48 keys
    uint4 w = ((const uint4*)base)[i * 256 + t];
    uint ww[4] = {w.x, w.y, w.z, w.w};
#pragma unroll
    for (int e = 0; e < 4; e++) {
      uint u = ww[e];
      uint mm = ((u >> 15) & 0x00010001u) * 0xffffu;
      v[4 * i + e] = (u ^ mm) | (0x80008000u & ~mm);
    }
    if (seg == 7 && (i * 256 + t) >= 1300) {   // pad cols >= 100000
      v[4 * i] = 0; v[4 * i + 1] = 0; v[4 * i + 2] = 0; v[4 * i + 3] = 0;
    }
  }
  {                                            // tail: 2 keys (never valid in seg 7)
    if (seg == 7) {
      v[24] = 0;
    } else {
      uint u = ((const uint*)base)[6144 + t];
      uint mm = ((u >> 15) & 0x00010001u) * 0xffffu;
      v[24] = (u ^ mm) | (0x80008000u & ~mm);
    }
  }
  // thread max
  uint mx = 0;
#pragma unroll
  for (int i = 0; i < 25; i++) {
    uint a = v[i] & 0xffffu, b = v[i] >> 16;
    mx = a > mx ? a : mx;
    mx = b > mx ? b : mx;
  }
  smax[t] = (ushort)mx;
  if (t == 0) shC = 0;
  __syncthreads();

  // L = 100th largest of 256 thread maxima (wave-local, no barriers)
  uint m0 = smax[lane], m1 = smax[lane + 64], m2 = smax[lane + 128], m3 = smax[lane + 192];
  uint lo = 0, hi = 65536;
  while (hi - lo > 1) {
    uint mid = (lo + hi) >> 1;
    int c = (m0 >= mid) + (m1 >= mid) + (m2 >= mid) + (m3 >= mid);
#pragma unroll
    for (int off = 32; off; off >>= 1) c += __shfl_xor(c, off);
    if (c >= KTOP) lo = mid; else hi = mid;
  }
  const uint L = lo;

  // compact keys >= L into LDS
#pragma unroll
  for (int i = 0; i < 25; i++) {
    uint a = v[i] & 0xffffu, b = v[i] >> 16;
    if (a >= L) { int p = atomicAdd(&shC, 1); if (p < LCAP2) list[p] = (ushort)a; }
    if (b >= L) { int p = atomicAdd(&shC, 1); if (p < LCAP2) list[p] = (ushort)b; }
  }
  __syncthreads();
  const int C = shC;

  uint Tkey;
  if (C <= LCAP2) {                            // common path: search LDS list
    uint lo2 = L, hi2 = 65536;
    while (hi2 - lo2 > 1) {
      uint mid = (lo2 + hi2) >> 1;
      int c = 0;
      for (int i = lane; i < C; i += 64) c += ((uint)list[i] >= mid) ? 1 : 0;
#pragma unroll
      for (int off = 32; off; off >>= 1) c += __shfl_xor(c, off);
      if (c >= KTOP) lo2 = mid; else hi2 = mid;
    }
    Tkey = lo2;
  } else {                                     // rare fallback: regs + barriers
    uint lo2 = L, hi2 = 65536;
    while (hi2 - lo2 > 1) {
      uint mid = (lo2 + hi2) >> 1;
      int c = 0;
#pragma unroll
      for (int i = 0; i < 25; i++) {
        c += ((v[i] & 0xffffu) >= mid) ? 1 : 0;
        c += ((v[i] >> 16) >= mid) ? 1 : 0;
      }
#pragma unroll
      for (int off = 32; off; off >>= 1) c += __shfl_xor(c, off);
      __syncthreads();
      if (lane == 0) ipart[t >> 6] = c;
      __syncthreads();
      c = ipart[0] + ipart[1] + ipart[2] + ipart[3];
      if (c >= KTOP) lo2 = mid; else hi2 = mid;
    }
    Tkey = lo2;
  }

  // emit segment top-100 multiset
  if (t == 0) shM = 0;
  __syncthreads();
  ushort* dst = cand + (size_t)q * 1024 + seg * 128;
  if (C <= LCAP2) {
    for (int i = t; i < C; i += 256) {
      uint u = list[i];
      if (u > Tkey) { int p = atomicAdd(&shM, 1); dst[p] = (ushort)u; }
    }
  } else {
#pragma unroll
    for (int i = 0; i < 25; i++) {
      uint a = v[i] & 0xffffu, b = v[i] >> 16;
      if (a > Tkey) { int p = atomicAdd(&shM, 1); dst[p] = (ushort)a; }
      if (b > Tkey) { int p = atomicAdd(&shM, 1); dst[p] = (ushort)b; }
    }
  }
  __syncthreads();
  for (int i = shM + t; i < KTOP; i += 256) dst[i] = (ushort)Tkey;
}

// ---- merge 8x100 candidates + mean + energy -> out (1 wave / row) --------
__global__ __launch_bounds__(64) void topk_fin(const ushort* __restrict__ cand,
                                               const float* __restrict__ energy,
                                               float* __restrict__ out) {
  const int q = blockIdx.x;
  const int t = threadIdx.x;
  const ushort* row = cand + (size_t)q * 1024;
  ushort kk[16];
#pragma unroll
  for (int s = 0; s < 8; s++) {
    kk[2 * s]     = row[s * 128 + t];                                  // t < 100
    kk[2 * s + 1] = (t + 64 < KTOP) ? row[s * 128 + 64 + t] : (ushort)0;
  }
  uint lo = 0, hi = 65536;
  while (hi - lo > 1) {
    uint mid = (lo + hi) >> 1;
    int c = 0;
#pragma unroll
    for (int i = 0; i < 16; i++) c += ((uint)kk[i] >= mid) ? 1 : 0;
#pragma unroll
    for (int off = 32; off; off >>= 1) c += __shfl_xor(c, off);
    if (c >= KTOP) lo = mid; else hi = mid;
  }
  const uint T = lo;
  float s = 0.f;
  int m = 0;
#pragma unroll
  for (int i = 0; i < 16; i++) {
    if ((uint)kk[i] > T) { s += o16f(kk[i]); m++; }
  }
#pragma unroll
  for (int off = 32; off; off >>= 1) {
    s += __shfl_xor(s, off);
    m += __shfl_xor(m, off);
  }
  if (t == 0) {
    float total = s + (float)(KTOP - m) * o16f((ushort)T);
    out[q] = -(total * (1.0f / KTOP)) * energy[q];
  }
}

extern "C" void kernel_launch(void* const* d_in, const int* in_sizes, int n_in,
                              void* d_out, int out_size, void* d_ws, size_t ws_size,
                              hipStream_t stream) {
  const float* feature     = (const float*)d_in[0];
  const float* logit       = (const float*)d_in[1];
  const float* bank_feas   = (const float*)d_in[2];
  const float* bank_logits = (const float*)d_in[3];
  // d_in[4] is K (device scalar) — problem instance fixes K = 100 (KTOP).
  float* out = (float*)d_out;

  char* ws = (char*)d_ws;
  size_t off = 0;
  auto take = [&](size_t bytes) -> char* {
    char* p = ws + off;
    off = (off + bytes + 255) & ~(size_t)255;
    return p;
  };
  float*  energy = (float*)take((size_t)QROWS * 4);
  ushort* a16    = (ushort*)take((size_t)QROWS * DDIM * 2);
  ushort* b16    = (ushort*)take((size_t)NPAD * DDIM * 2);
  ushort* sims   = (ushort*)take((size_t)QROWS * NPAD * 2);
  ushort* cand   = (ushort*)take((size_t)QROWS * 1024 * 2);
  if (off > ws_size) return;  // needs ~1.02 GB

  bank_prep<<<dim3(NPAD / 4), dim3(256), 0, stream>>>(bank_logits, bank_feas, b16);
  lse_rows <<<dim3(QROWS / 4), dim3(256), 0, stream>>>(logit, energy, QROWS, CDIM);
  feat_norm<<<dim3(QROWS / 4), dim3(256), 0, stream>>>(feature, a16);
  gemm_sims<<<dim3(GNWG), dim3(512), 0, stream>>>(a16, b16, sims);
  topk_seg <<<dim3(QROWS * 8), dim3(256), 0, stream>>>(sims, cand);
  topk_fin <<<dim3(QROWS), dim3(64), 0, stream>>>(cand, energy, out);
}

// Round 7
// 1346.915 us; speedup vs baseline: 2.2213x; 1.0797x over previous
//
#include <hip/hip_runtime.h>
#include <hip/hip_bf16.h>

#define QROWS 4096
#define DDIM  768
#define NBANK 100000
#define CDIM  1000
#define KTOP  100
#define NPAD  102400                 // padded bank cols
#define SEGW2 12800                  // NPAD/8 keys per top-k segment
#define LCAP2 4096                   // LDS candidate cap in topk_seg

typedef float floatx4 __attribute__((ext_vector_type(4)));
typedef short bf16x8 __attribute__((ext_vector_type(8)));

__device__ inline ushort f2bf(float f) {            // f32 -> bf16 RNE
  uint b = __float_as_uint(f);
  uint r = b + 0x7fffu + ((b >> 16) & 1u);
  return (ushort)(r >> 16);
}
__device__ inline float o16f(ushort u) {            // ordered u16 -> f32 value
  ushort b = (u & 0x8000) ? (ushort)(u & 0x7fff) : (ushort)~u;
  return __uint_as_float((uint)b << 16);
}

// ---- bank_prep: conf=LSE(logits), b16[row]=bf16(feas*conf/||feas||) ------
__global__ __launch_bounds__(256) void bank_prep(const float* __restrict__ logits,
                                                 const float* __restrict__ feas,
                                                 ushort* __restrict__ b16) {
  int row = blockIdx.x * 4 + (threadIdx.x >> 6);
  int lane = threadIdx.x & 63;
  if (row >= NPAD) return;
  ushort4* dst = (ushort4*)(b16 + (size_t)row * DDIM);
  if (row >= NBANK) {
#pragma unroll
    for (int j = 0; j < 3; j++) dst[lane + j * 64] = make_ushort4(0, 0, 0, 0);
    return;
  }
  const float4* lp = (const float4*)(logits + (size_t)row * CDIM);
  float4 v[4];
  float m = -3.0e38f;
#pragma unroll
  for (int j = 0; j < 4; j++) {
    int idx = lane + j * 64;
    if (idx < CDIM / 4) {
      v[j] = lp[idx];
      m = fmaxf(m, fmaxf(fmaxf(v[j].x, v[j].y), fmaxf(v[j].z, v[j].w)));
    } else {
      v[j] = make_float4(-3.0e38f, -3.0e38f, -3.0e38f, -3.0e38f);
    }
  }
#pragma unroll
  for (int off = 32; off; off >>= 1) m = fmaxf(m, __shfl_xor(m, off));
  float s = 0.f;
#pragma unroll
  for (int j = 0; j < 4; j++)
    s += __expf(v[j].x - m) + __expf(v[j].y - m) +
         __expf(v[j].z - m) + __expf(v[j].w - m);
#pragma unroll
  for (int off = 32; off; off >>= 1) s += __shfl_xor(s, off);
  float conf = m + __logf(s);
  const float4* fp = (const float4*)(feas + (size_t)row * DDIM);
  float4 w[3];
  float ss = 0.f;
#pragma unroll
  for (int j = 0; j < 3; j++) {
    w[j] = fp[lane + j * 64];
    ss += w[j].x * w[j].x + w[j].y * w[j].y + w[j].z * w[j].z + w[j].w * w[j].w;
  }
#pragma unroll
  for (int off = 32; off; off >>= 1) ss += __shfl_xor(ss, off);
  float scale = conf / sqrtf(ss);
#pragma unroll
  for (int j = 0; j < 3; j++)
    dst[lane + j * 64] = make_ushort4(f2bf(w[j].x * scale), f2bf(w[j].y * scale),
                                      f2bf(w[j].z * scale), f2bf(w[j].w * scale));
}

// ---- row-wise logsumexp for logit -> energy ------------------------------
__global__ __launch_bounds__(256) void lse_rows(const float* __restrict__ x,
                                                float* __restrict__ out,
                                                int nrows, int ncols) {
  int row = blockIdx.x * 4 + (threadIdx.x >> 6);
  int lane = threadIdx.x & 63;
  if (row >= nrows) return;
  const float4* rp = (const float4*)(x + (size_t)row * ncols);
  int n4 = ncols >> 2;
  float4 v[4];
  float m = -3.0e38f;
#pragma unroll
  for (int j = 0; j < 4; j++) {
    int idx = lane + j * 64;
    if (idx < n4) {
      v[j] = rp[idx];
      m = fmaxf(m, fmaxf(fmaxf(v[j].x, v[j].y), fmaxf(v[j].z, v[j].w)));
    } else {
      v[j] = make_float4(-3.0e38f, -3.0e38f, -3.0e38f, -3.0e38f);
    }
  }
#pragma unroll
  for (int off = 32; off; off >>= 1) m = fmaxf(m, __shfl_xor(m, off));
  float s = 0.f;
#pragma unroll
  for (int j = 0; j < 4; j++)
    s += __expf(v[j].x - m) + __expf(v[j].y - m) +
         __expf(v[j].z - m) + __expf(v[j].w - m);
#pragma unroll
  for (int off = 32; off; off >>= 1) s += __shfl_xor(s, off);
  if (lane == 0) out[row] = m + __logf(s);
}

// ---- a16[q][d] = bf16(feature/||feature||) -------------------------------
__global__ __launch_bounds__(256) void feat_norm(const float* __restrict__ x,
                                                 ushort* __restrict__ y) {
  int row = blockIdx.x * 4 + (threadIdx.x >> 6);
  int lane = threadIdx.x & 63;
  if (row >= QROWS) return;
  const float4* rp = (const float4*)(x + (size_t)row * DDIM);
  float4 v[3];
  float ss = 0.f;
#pragma unroll
  for (int j = 0; j < 3; j++) {
    v[j] = rp[lane + j * 64];
    ss += v[j].x * v[j].x + v[j].y * v[j].y + v[j].z * v[j].z + v[j].w * v[j].w;
  }
#pragma unroll
  for (int off = 32; off; off >>= 1) ss += __shfl_xor(ss, off);
  float rn = 1.0f / sqrtf(ss);
  ushort4* dst = (ushort4*)(y + (size_t)row * DDIM);
#pragma unroll
  for (int j = 0; j < 3; j++)
    dst[lane + j * 64] = make_ushort4(f2bf(v[j].x * rn), f2bf(v[j].y * rn),
                                      f2bf(v[j].z * rn), f2bf(v[j].w * rn));
}

// ---- bf16 MFMA GEMM v5: 256x256 tile, per-wave 128x64, BK=64 --------------
// B-frags read once per K-tile into regs (8 b128), A per 2-row quadrant
// (4 b128 x 4 phases) -> 0.375 b128/MFMA. 2-buffer dbuf w/ half-tile
// recycling: stageA(s+1) at tile entry, mid-barrier frees B-half, then
// stageB(s+2). Counted vmcnt(4) steady state. 3-bit XOR swizzle (0-conflict,
// verified r6). 2 barriers/K-tile, no intra-phase barriers (wave drift ->
// role split -> setprio pays).
#define GBM 256
#define GBN 256
#define GBK 64
#define NT  (DDIM / GBK)                       // 12 K-tiles
#define GNWG ((QROWS / GBM) * (NPAD / GBN))    // 16*400 = 6400

__device__ inline void load_lds16(const void* g, void* l) {
  __builtin_amdgcn_global_load_lds(
      (const __attribute__((address_space(1))) void*)g,
      (__attribute__((address_space(3))) void*)l, 16, 0, 0);
}

__global__ __launch_bounds__(512, 2) void gemm_sims(const ushort* __restrict__ A,
                                                    const ushort* __restrict__ B,
                                                    ushort* __restrict__ C) {
  __shared__ ushort lds[2 * 32768];            // 2 bufs x (A 16384 | B 16384), 128 KB
  const int tid = threadIdx.x;
  const int lane = tid & 63;
  const int wid = tid >> 6;
  const int wm = wid >> 2, wn = wid & 3;       // 2(M) x 4(N) waves, 128x64 each
  const int lr = lane & 15, lg = lane >> 4;

  // XCD chunking (6400%8==0, bijective) + 4x4 supertiles
  int flat = blockIdx.x;
  int wgid = (flat & 7) * (GNWG / 8) + (flat >> 3);
  int sup = wgid >> 4, wi = wgid & 15;
  int q_idx = (sup & 3) * 4 + (wi & 3);        // 0..15
  int n_idx = (sup >> 2) * 4 + (wi >> 2);      // 0..399
  const int qBase = q_idx * GBM;
  const int nBase = n_idx * GBN;

  // staging geometry: 8-row groups, slot sub = lane&7, source col pre-swizzled
  const int rin = lane >> 3;
  const int cswu = ((lane & 7) ^ rin) << 3;    // ushort offset in 64-ushort row

  auto stageA = [&](int t, int buf) {          // 4 x load_lds16 / thread
#pragma unroll
    for (int r = 0; r < 4; r++) {
      int G = r * 8 + wid;                     // 0..31, wave-uniform
      int row = qBase + G * 8 + rin;
      load_lds16(A + (size_t)row * DDIM + t * GBK + cswu,
                 lds + buf * 32768 + G * 512 + lane * 8);
    }
  };
  auto stageB = [&](int t, int buf) {
#pragma unroll
    for (int r = 0; r < 4; r++) {
      int G = r * 8 + wid;
      int row = nBase + G * 8 + rin;
      load_lds16(B + (size_t)row * DDIM + t * GBK + cswu,
                 lds + buf * 32768 + 16384 + G * 512 + lane * 8);
    }
  };

  floatx4 acc[8][4] = {};
  const int rsw = (lr & 7) << 3;               // read-side ushort xor

  stageA(0, 0); stageB(0, 0); stageA(1, 1); stageB(1, 1);   // 16 loads

  for (int s = 0; s < NT; s++) {
    const int buf = s & 1;
    if (s == 0)           asm volatile("s_waitcnt vmcnt(8)" ::: "memory");
    else if (s == NT - 1) asm volatile("s_waitcnt vmcnt(0)" ::: "memory");
    else                  asm volatile("s_waitcnt vmcnt(4)" ::: "memory");
    __builtin_amdgcn_s_barrier();
    __builtin_amdgcn_sched_barrier(0);
    if (s >= 1 && s + 1 < NT) stageA(s + 1, buf ^ 1);   // A-half of other buf
    const ushort* Ab = lds + buf * 32768;
    const ushort* Bb = Ab + 16384;

    // ---- phase 0: read ALL B frags (regs for whole K-tile) + A quadrant 0
    bf16x8 bfr[4][2], af[2][2];
#pragma unroll
    for (int n = 0; n < 4; n++)
#pragma unroll
      for (int kk = 0; kk < 2; kk++)
        bfr[n][kk] = *(const bf16x8*)(Bb + (wn * 64 + n * 16 + lr) * 64 +
                                      ((kk * 32 + lg * 8) ^ rsw));
#pragma unroll
    for (int m = 0; m < 2; m++)
#pragma unroll
      for (int kk = 0; kk < 2; kk++)
        af[m][kk] = *(const bf16x8*)(Ab + (wm * 128 + m * 16 + lr) * 64 +
                                     ((kk * 32 + lg * 8) ^ rsw));
    __builtin_amdgcn_s_setprio(1);
#pragma unroll
    for (int m = 0; m < 2; m++)
#pragma unroll
      for (int n = 0; n < 4; n++)
#pragma unroll
        for (int kk = 0; kk < 2; kk++)
          acc[m][n] = __builtin_amdgcn_mfma_f32_16x16x32_bf16(af[m][kk], bfr[n][kk],
                                                              acc[m][n], 0, 0, 0);
    __builtin_amdgcn_s_setprio(0);
    __builtin_amdgcn_s_barrier();              // mid: B-half fully consumed
    __builtin_amdgcn_sched_barrier(0);
    if (s + 2 < NT) stageB(s + 2, buf);        // recycle this buf's B-half

    // ---- phases 1..3: A quadrants, B from regs, no barriers ----
#pragma unroll
    for (int q = 1; q < 4; q++) {
      bf16x8 aq[2][2];
#pragma unroll
      for (int m = 0; m < 2; m++)
#pragma unroll
        for (int kk = 0; kk < 2; kk++)
          aq[m][kk] = *(const bf16x8*)(Ab + (wm * 128 + (2 * q + m) * 16 + lr) * 64 +
                                       ((kk * 32 + lg * 8) ^ rsw));
      __builtin_amdgcn_s_setprio(1);
#pragma unroll
      for (int m = 0; m < 2; m++)
#pragma unroll
        for (int n = 0; n < 4; n++)
#pragma unroll
          for (int kk = 0; kk < 2; kk++)
            acc[2 * q + m][n] = __builtin_amdgcn_mfma_f32_16x16x32_bf16(
                aq[m][kk], bfr[n][kk], acc[2 * q + m][n], 0, 0, 0);
      __builtin_amdgcn_s_setprio(0);
    }
  }

  // epilogue: C write (bf16)
#pragma unroll
  for (int m = 0; m < 8; m++)
#pragma unroll
    for (int n = 0; n < 4; n++) {
      int q = qBase + wm * 128 + m * 16 + lg * 4;
      int col = nBase + wn * 64 + n * 16 + lr;
      ushort* cp = C + (size_t)q * NPAD + col;
#pragma unroll
      for (int r = 0; r < 4; r++) cp[(size_t)r * NPAD] = f2bf(acc[m][n][r]);
    }
}

// ---- per-segment exact top-K multiset: ballot compaction, no per-key atomics
__global__ __launch_bounds__(256) void topk_seg(const ushort* __restrict__ sims,
                                                ushort* __restrict__ cand) {
  __shared__ ushort smax[256];
  __shared__ ushort list[LCAP2];
  __shared__ int shC, shM, ipart[4];
  const int t = threadIdx.x;
  const int lane = t & 63;
  const int q = blockIdx.x >> 3, seg = blockIdx.x & 7;
  const ushort* base = sims + (size_t)q * NPAD + seg * SEGW2;

  uint v[25];                                  // 50 ordered u16 keys
#pragma unroll
  for (int i = 0; i < 6; i++) {                // 6 x uint4 = 48 keys
    uint4 w = ((const uint4*)base)[i * 256 + t];
    uint ww[4] = {w.x, w.y, w.z, w.w};
#pragma unroll
    for (int e = 0; e < 4; e++) {
      uint u = ww[e];
      uint mm = ((u >> 15) & 0x00010001u) * 0xffffu;
      v[4 * i + e] = (u ^ mm) | (0x80008000u & ~mm);
    }
    if (seg == 7 && (i * 256 + t) >= 1300) {   // pad cols >= 100000
      v[4 * i] = 0; v[4 * i + 1] = 0; v[4 * i + 2] = 0; v[4 * i + 3] = 0;
    }
  }
  {                                            // tail: 2 keys (never valid in seg 7)
    if (seg == 7) {
      v[24] = 0;
    } else {
      uint u = ((const uint*)base)[6144 + t];
      uint mm = ((u >> 15) & 0x00010001u) * 0xffffu;
      v[24] = (u ^ mm) | (0x80008000u & ~mm);
    }
  }
  // thread max
  uint mx = 0;
#pragma unroll
  for (int i = 0; i < 25; i++) {
    uint a = v[i] & 0xffffu, b = v[i] >> 16;
    mx = a > mx ? a : mx;
    mx = b > mx ? b : mx;
  }
  smax[t] = (ushort)mx;
  if (t == 0) shC = 0;
  __syncthreads();

  // L = 100th largest of 256 thread maxima (wave-local, no barriers)
  uint m0 = smax[lane], m1 = smax[lane + 64], m2 = smax[lane + 128], m3 = smax[lane + 192];
  uint lo = 0, hi = 65536;
  while (hi - lo > 1) {
    uint mid = (lo + hi) >> 1;
    int c = (m0 >= mid) + (m1 >= mid) + (m2 >= mid) + (m3 >= mid);
#pragma unroll
    for (int off = 32; off; off >>= 1) c += __shfl_xor(c, off);
    if (c >= KTOP) lo = mid; else hi = mid;
  }
  const uint L = lo;

  // ---- ballot compaction of keys >= L into LDS (1 atomic per wave) ----
  const unsigned long long ltm = (1ull << lane) - 1ull;
  int tot = 0;
#pragma unroll
  for (int i = 0; i < 25; i++) {
    tot += __popcll(__ballot((v[i] & 0xffffu) >= L));
    tot += __popcll(__ballot((v[i] >> 16) >= L));
  }
  int wb = 0;
  if (lane == 0) wb = atomicAdd(&shC, tot);
  wb = __shfl(wb, 0);
  int run = wb;
#pragma unroll
  for (int i = 0; i < 25; i++) {
    uint a = v[i] & 0xffffu, b = v[i] >> 16;
    unsigned long long ma = __ballot(a >= L);
    if (a >= L) { int p = run + __popcll(ma & ltm); if (p < LCAP2) list[p] = (ushort)a; }
    run += __popcll(ma);
    unsigned long long mb = __ballot(b >= L);
    if (b >= L) { int p = run + __popcll(mb & ltm); if (p < LCAP2) list[p] = (ushort)b; }
    run += __popcll(mb);
  }
  __syncthreads();
  const int C = shC;

  uint Tkey;
  if (C <= LCAP2) {                            // common path: search LDS list
    uint lo2 = L, hi2 = 65536;
    while (hi2 - lo2 > 1) {
      uint mid = (lo2 + hi2) >> 1;
      int c = 0;
      for (int i = lane; i < C; i += 64) c += ((uint)list[i] >= mid) ? 1 : 0;
#pragma unroll
      for (int off = 32; off; off >>= 1) c += __shfl_xor(c, off);
      if (c >= KTOP) lo2 = mid; else hi2 = mid;
    }
    Tkey = lo2;
  } else {                                     // rare fallback: regs + barriers
    uint lo2 = L, hi2 = 65536;
    while (hi2 - lo2 > 1) {
      uint mid = (lo2 + hi2) >> 1;
      int c = 0;
#pragma unroll
      for (int i = 0; i < 25; i++) {
        c += ((v[i] & 0xffffu) >= mid) ? 1 : 0;
        c += ((v[i] >> 16) >= mid) ? 1 : 0;
      }
#pragma unroll
      for (int off = 32; off; off >>= 1) c += __shfl_xor(c, off);
      __syncthreads();
      if (lane == 0) ipart[t >> 6] = c;
      __syncthreads();
      c = ipart[0] + ipart[1] + ipart[2] + ipart[3];
      if (c >= KTOP) lo2 = mid; else hi2 = mid;
    }
    Tkey = lo2;
  }

  // emit segment top-100 multiset (m <= 99 strict keys + tie fill)
  if (t == 0) shM = 0;
  __syncthreads();
  ushort* dst = cand + (size_t)q * 1024 + seg * 128;
  if (C <= LCAP2) {
    for (int i = t; i < C; i += 256) {
      uint u = list[i];
      if (u > Tkey) { int p = atomicAdd(&shM, 1); dst[p] = (ushort)u; }
    }
  } else {
#pragma unroll
    for (int i = 0; i < 25; i++) {
      uint a = v[i] & 0xffffu, b = v[i] >> 16;
      if (a > Tkey) { int p = atomicAdd(&shM, 1); dst[p] = (ushort)a; }
      if (b > Tkey) { int p = atomicAdd(&shM, 1); dst[p] = (ushort)b; }
    }
  }
  __syncthreads();
  for (int i = shM + t; i < KTOP; i += 256) dst[i] = (ushort)Tkey;
}

// ---- merge 8x100 candidates + mean + energy -> out (1 wave / row) --------
__global__ __launch_bounds__(64) void topk_fin(const ushort* __restrict__ cand,
                                               const float* __restrict__ energy,
                                               float* __restrict__ out) {
  const int q = blockIdx.x;
  const int t = threadIdx.x;
  const ushort* row = cand + (size_t)q * 1024;
  ushort kk[16];
#pragma unroll
  for (int s = 0; s < 8; s++) {
    kk[2 * s]     = row[s * 128 + t];                                  // t < 100
    kk[2 * s + 1] = (t + 64 < KTOP) ? row[s * 128 + 64 + t] : (ushort)0;
  }
  uint lo = 0, hi = 65536;
  while (hi - lo > 1) {
    uint mid = (lo + hi) >> 1;
    int c = 0;
#pragma unroll
    for (int i = 0; i < 16; i++) c += ((uint)kk[i] >= mid) ? 1 : 0;
#pragma unroll
    for (int off = 32; off; off >>= 1) c += __shfl_xor(c, off);
    if (c >= KTOP) lo = mid; else hi = mid;
  }
  const uint T = lo;
  float s = 0.f;
  int m = 0;
#pragma unroll
  for (int i = 0; i < 16; i++) {
    if ((uint)kk[i] > T) { s += o16f(kk[i]); m++; }
  }
#pragma unroll
  for (int off = 32; off; off >>= 1) {
    s += __shfl_xor(s, off);
    m += __shfl_xor(m, off);
  }
  if (t == 0) {
    float total = s + (float)(KTOP - m) * o16f((ushort)T);
    out[q] = -(total * (1.0f / KTOP)) * energy[q];
  }
}

extern "C" void kernel_launch(void* const* d_in, const int* in_sizes, int n_in,
                              void* d_out, int out_size, void* d_ws, size_t ws_size,
                              hipStream_t stream) {
  const float* feature     = (const float*)d_in[0];
  const float* logit       = (const float*)d_in[1];
  const float* bank_feas   = (const float*)d_in[2];
  const float* bank_logits = (const float*)d_in[3];
  // d_in[4] is K (device scalar) — problem instance fixes K = 100 (KTOP).
  float* out = (float*)d_out;

  char* ws = (char*)d_ws;
  size_t off = 0;
  auto take = [&](size_t bytes) -> char* {
    char* p = ws + off;
    off = (off + bytes + 255) & ~(size_t)255;
    return p;
  };
  float*  energy = (float*)take((size_t)QROWS * 4);
  ushort* a16    = (ushort*)take((size_t)QROWS * DDIM * 2);
  ushort* b16    = (ushort*)take((size_t)NPAD * DDIM * 2);
  ushort* sims   = (ushort*)take((size_t)QROWS * NPAD * 2);
  ushort* cand   = (ushort*)take((size_t)QROWS * 1024 * 2);
  if (off > ws_size) return;  // needs ~1.02 GB

  bank_prep<<<dim3(NPAD / 4), dim3(256), 0, stream>>>(bank_logits, bank_feas, b16);
  lse_rows <<<dim3(QROWS / 4), dim3(256), 0, stream>>>(logit, energy, QROWS, CDIM);
  feat_norm<<<dim3(QROWS / 4), dim3(256), 0, stream>>>(feature, a16);
  gemm_sims<<<dim3(GNWG), dim3(512), 0, stream>>>(a16, b16, sims);
  topk_seg <<<dim3(QROWS * 8), dim3(256), 0, stream>>>(sims, cand);
  topk_fin <<<dim3(QROWS), dim3(64), 0, stream>>>(cand, energy, out);
}

// Round 8
// 1122.077 us; speedup vs baseline: 2.6664x; 1.2004x over previous
//
#include <hip/hip_runtime.h>
#include <hip/hip_bf16.h>

#define QROWS 4096
#define DDIM  768
#define NBANK 100000
#define CDIM  1000
#define KTOP  100
#define NPAD  102400                 // padded bank cols
#define SEGW2 12800                  // NPAD/8 keys per top-k segment
#define LCAP2 4096                   // LDS candidate cap in topk_seg

typedef float floatx4 __attribute__((ext_vector_type(4)));
typedef short bf16x8 __attribute__((ext_vector_type(8)));

__device__ inline ushort f2bf(float f) {            // f32 -> bf16 RNE
  uint b = __float_as_uint(f);
  uint r = b + 0x7fffu + ((b >> 16) & 1u);
  return (ushort)(r >> 16);
}
__device__ inline float o16f(ushort u) {            // ordered u16 -> f32 value
  ushort b = (u & 0x8000) ? (ushort)(u & 0x7fff) : (ushort)~u;
  return __uint_as_float((uint)b << 16);
}

// ---- row-wise logsumexp (ncols<=1024), 1 wave/row: used for bank conf AND energy
__global__ __launch_bounds__(256) void lse_rows(const float* __restrict__ x,
                                                float* __restrict__ out,
                                                int nrows, int ncols) {
  int row = blockIdx.x * 4 + (threadIdx.x >> 6);
  int lane = threadIdx.x & 63;
  if (row >= nrows) return;
  const float4* rp = (const float4*)(x + (size_t)row * ncols);
  int n4 = ncols >> 2;
  float4 v[4];
  float m = -3.0e38f;
#pragma unroll
  for (int j = 0; j < 4; j++) {
    int idx = lane + j * 64;
    if (idx < n4) {
      v[j] = rp[idx];
      m = fmaxf(m, fmaxf(fmaxf(v[j].x, v[j].y), fmaxf(v[j].z, v[j].w)));
    } else {
      v[j] = make_float4(-3.0e38f, -3.0e38f, -3.0e38f, -3.0e38f);
    }
  }
#pragma unroll
  for (int off = 32; off; off >>= 1) m = fmaxf(m, __shfl_xor(m, off));
  float s = 0.f;
#pragma unroll
  for (int j = 0; j < 4; j++)
    s += __expf(v[j].x - m) + __expf(v[j].y - m) +
         __expf(v[j].z - m) + __expf(v[j].w - m);
#pragma unroll
  for (int off = 32; off; off >>= 1) s += __shfl_xor(s, off);
  if (lane == 0) out[row] = m + __logf(s);
}

// ---- bank_sc: b16[row] = bf16(feas * conf/||feas||), zero pad rows -------
__global__ __launch_bounds__(256) void bank_sc(const float* __restrict__ feas,
                                               const float* __restrict__ conf,
                                               ushort* __restrict__ b16) {
  int row = blockIdx.x * 4 + (threadIdx.x >> 6);
  int lane = threadIdx.x & 63;
  if (row >= NPAD) return;
  ushort4* dst = (ushort4*)(b16 + (size_t)row * DDIM);
  if (row >= NBANK) {
#pragma unroll
    for (int j = 0; j < 3; j++) dst[lane + j * 64] = make_ushort4(0, 0, 0, 0);
    return;
  }
  const float4* fp = (const float4*)(feas + (size_t)row * DDIM);
  float4 w[3];
  float ss = 0.f;
#pragma unroll
  for (int j = 0; j < 3; j++) {
    w[j] = fp[lane + j * 64];
    ss += w[j].x * w[j].x + w[j].y * w[j].y + w[j].z * w[j].z + w[j].w * w[j].w;
  }
#pragma unroll
  for (int off = 32; off; off >>= 1) ss += __shfl_xor(ss, off);
  float s = conf[row] / sqrtf(ss);
#pragma unroll
  for (int j = 0; j < 3; j++)
    dst[lane + j * 64] = make_ushort4(f2bf(w[j].x * s), f2bf(w[j].y * s),
                                      f2bf(w[j].z * s), f2bf(w[j].w * s));
}

// ---- a16[q][d] = bf16(feature/||feature||) -------------------------------
__global__ __launch_bounds__(256) void feat_norm(const float* __restrict__ x,
                                                 ushort* __restrict__ y) {
  int row = blockIdx.x * 4 + (threadIdx.x >> 6);
  int lane = threadIdx.x & 63;
  if (row >= QROWS) return;
  const float4* rp = (const float4*)(x + (size_t)row * DDIM);
  float4 v[3];
  float ss = 0.f;
#pragma unroll
  for (int j = 0; j < 3; j++) {
    v[j] = rp[lane + j * 64];
    ss += v[j].x * v[j].x + v[j].y * v[j].y + v[j].z * v[j].z + v[j].w * v[j].w;
  }
#pragma unroll
  for (int off = 32; off; off >>= 1) ss += __shfl_xor(ss, off);
  float rn = 1.0f / sqrtf(ss);
  ushort4* dst = (ushort4*)(y + (size_t)row * DDIM);
#pragma unroll
  for (int j = 0; j < 3; j++)
    dst[lane + j * 64] = make_ushort4(f2bf(v[j].x * rn), f2bf(v[j].y * rn),
                                      f2bf(v[j].z * rn), f2bf(v[j].w * rn));
}

// ---- bf16 MFMA GEMM v6: m201 8-phase schedule, 256x256, BK=64 -------------
// 8 waves (2M x 4N), per-wave 128x64, 2 K-tiles/iteration, 8 phases/iter.
// Per phase: {ds_read quadrant frags; stage 1 half-tile; barrier; lgkmcnt(0);
// sched_barrier; setprio(1); 16 MFMA; setprio(0); [vmcnt(4) at ph4/ph8];
// barrier}. 3-bit XOR swizzle (0-conflict, verified r6). Counted vmcnt only.
#define GBM 256
#define GBN 256
#define GBK 64
#define NT  (DDIM / GBK)                       // 12 K-tiles, 6 iterations
#define GNWG ((QROWS / GBM) * (NPAD / GBN))    // 16*400 = 6400

__device__ inline void load_lds16(const void* g, void* l) {
  __builtin_amdgcn_global_load_lds(
      (const __attribute__((address_space(1))) void*)g,
      (__attribute__((address_space(3))) void*)l, 16, 0, 0);
}

// PHASE: BUF/Q are literals (acc indices must be compile-time, rule #20).
#define PHASE(BUF, Q, LOADB, STAGE_STMT, VM_STMT)                              \
  {                                                                            \
    const ushort* Ab = lds + (BUF) * 32768;                                    \
    if (LOADB) {                                                               \
      const ushort* Bb = Ab + 16384;                                           \
      _Pragma("unroll") for (int n = 0; n < 4; n++)                            \
        _Pragma("unroll") for (int kk = 0; kk < 2; kk++)                       \
          bfr[n][kk] = *(const bf16x8*)(Bb + (wn * 64 + n * 16 + lr) * 64 +    \
                                        ((kk * 32 + lg * 8) ^ rsw));           \
    }                                                                          \
    bf16x8 af[2][2];                                                           \
    _Pragma("unroll") for (int m = 0; m < 2; m++)                              \
      _Pragma("unroll") for (int kk = 0; kk < 2; kk++)                         \
        af[m][kk] = *(const bf16x8*)(Ab + (wm * 128 + (2 * (Q) + m) * 16 + lr) \
                                     * 64 + ((kk * 32 + lg * 8) ^ rsw));       \
    STAGE_STMT;                                                                \
    __builtin_amdgcn_s_barrier();                                              \
    asm volatile("s_waitcnt lgkmcnt(0)" ::: "memory");                         \
    __builtin_amdgcn_sched_barrier(0);                                         \
    __builtin_amdgcn_s_setprio(1);                                             \
    _Pragma("unroll") for (int m = 0; m < 2; m++)                              \
      _Pragma("unroll") for (int n = 0; n < 4; n++)                            \
        _Pragma("unroll") for (int kk = 0; kk < 2; kk++)                       \
          acc[2 * (Q) + m][n] = __builtin_amdgcn_mfma_f32_16x16x32_bf16(       \
              af[m][kk], bfr[n][kk], acc[2 * (Q) + m][n], 0, 0, 0);            \
    __builtin_amdgcn_s_setprio(0);                                             \
    VM_STMT;                                                                   \
    __builtin_amdgcn_s_barrier();                                              \
  }

__global__ __launch_bounds__(512) void gemm_sims(const ushort* __restrict__ A,
                                                 const ushort* __restrict__ B,
                                                 ushort* __restrict__ C) {
  __shared__ ushort lds[2 * 32768];            // 2 bufs x (A 16K | B 16K) ushorts
  const int tid = threadIdx.x;
  const int lane = tid & 63;
  const int wid = tid >> 6;
  const int wm = wid >> 2, wn = wid & 3;       // 2(M) x 4(N) waves, 128x64 each
  const int lr = lane & 15, lg = lane >> 4;

  // XCD chunking (6400%8==0, bijective) + 4x4 supertiles
  int flat = blockIdx.x;
  int wgid = (flat & 7) * (GNWG / 8) + (flat >> 3);
  int sup = wgid >> 4, wi = wgid & 15;
  int q_idx = (sup & 3) * 4 + (wi & 3);        // 0..15
  int n_idx = (sup >> 2) * 4 + (wi >> 2);      // 0..399
  const int qBase = q_idx * GBM;
  const int nBase = n_idx * GBN;

  // staging: 8-row groups; LDS dest linear; source col pre-swizzled (rule #21)
  const int rin = lane >> 3;
  const int cswu = ((lane & 7) ^ rin) << 3;    // ushort offset in 64-ushort row
  const int rsw = (lr & 7) << 3;               // read-side ushort xor

  // half h of A-tile t -> groups G in [16h,16h+16); buf = t&1
  auto stageAh = [&](int t, int h) {
    if (t < NT) {
#pragma unroll
      for (int r = 2 * h; r < 2 * h + 2; r++) {
        int G = r * 8 + wid;
        int row = qBase + G * 8 + rin;
        load_lds16(A + (size_t)row * DDIM + t * GBK + cswu,
                   lds + (t & 1) * 32768 + G * 512 + lane * 8);
      }
    }
  };
  auto stageBh = [&](int t, int h) {
    if (t < NT) {
#pragma unroll
      for (int r = 2 * h; r < 2 * h + 2; r++) {
        int G = r * 8 + wid;
        int row = nBase + G * 8 + rin;
        load_lds16(B + (size_t)row * DDIM + t * GBK + cswu,
                   lds + (t & 1) * 32768 + 16384 + G * 512 + lane * 8);
      }
    }
  };

  floatx4 acc[8][4] = {};
  bf16x8 bfr[4][2];

  // prologue: B(0), A(0), B(1) staged in steady-state issue order
  stageBh(0, 0); stageBh(0, 1);
  stageAh(0, 0); stageAh(0, 1);
  stageBh(1, 0); stageBh(1, 1);
  asm volatile("s_waitcnt vmcnt(4)" ::: "memory");   // A(0),B(0) landed
  __builtin_amdgcn_s_barrier();

#pragma unroll 1
  for (int i = 0; i < NT / 2; i++) {
    const int t0 = 2 * i;
    const bool last = (i == NT / 2 - 1);
    // tile t0 (buf 0)
    PHASE(0, 0, true,  stageAh(t0 + 1, 0), );
    PHASE(0, 1, false, stageAh(t0 + 1, 1), );
    PHASE(0, 2, false, stageBh(t0 + 2, 0), );
    PHASE(0, 3, false, stageBh(t0 + 2, 1),
          if (last) { asm volatile("s_waitcnt vmcnt(0)" ::: "memory"); }
          else      { asm volatile("s_waitcnt vmcnt(4)" ::: "memory"); });
    // tile t0+1 (buf 1)
    PHASE(1, 0, true,  stageAh(t0 + 2, 0), );
    PHASE(1, 1, false, stageAh(t0 + 2, 1), );
    PHASE(1, 2, false, stageBh(t0 + 3, 0), );
    PHASE(1, 3, false, stageBh(t0 + 3, 1),
          if (!last) { asm volatile("s_waitcnt vmcnt(4)" ::: "memory"); });
  }

  // epilogue: C write (bf16)
#pragma unroll
  for (int m = 0; m < 8; m++)
#pragma unroll
    for (int n = 0; n < 4; n++) {
      int q = qBase + wm * 128 + m * 16 + lg * 4;
      int col = nBase + wn * 64 + n * 16 + lr;
      ushort* cp = C + (size_t)q * NPAD + col;
#pragma unroll
      for (int r = 0; r < 4; r++) cp[(size_t)r * NPAD] = f2bf(acc[m][n][r]);
    }
}

// ---- per-segment exact top-K multiset: ballot counting + ballot compaction
__global__ __launch_bounds__(256) void topk_seg(const ushort* __restrict__ sims,
                                                ushort* __restrict__ cand) {
  __shared__ ushort smax[256];
  __shared__ ushort list[LCAP2];
  __shared__ int shC, shM, ipart[4];
  const int t = threadIdx.x;
  const int lane = t & 63;
  const int q = blockIdx.x >> 3, seg = blockIdx.x & 7;
  const ushort* base = sims + (size_t)q * NPAD + seg * SEGW2;

  uint v[25];                                  // 50 ordered u16 keys
#pragma unroll
  for (int i = 0; i < 6; i++) {                // 6 x uint4 = 48 keys
    uint4 w = ((const uint4*)base)[i * 256 + t];
    uint ww[4] = {w.x, w.y, w.z, w.w};
#pragma unroll
    for (int e = 0; e < 4; e++) {
      uint u = ww[e];
      uint mm = ((u >> 15) & 0x00010001u) * 0xffffu;
      v[4 * i + e] = (u ^ mm) | (0x80008000u & ~mm);
    }
    if (seg == 7 && (i * 256 + t) >= 1300) {   // pad cols >= 100000
      v[4 * i] = 0; v[4 * i + 1] = 0; v[4 * i + 2] = 0; v[4 * i + 3] = 0;
    }
  }
  {                                            // tail: 2 keys (invalid in seg 7)
    if (seg == 7) {
      v[24] = 0;
    } else {
      uint u = ((const uint*)base)[6144 + t];
      uint mm = ((u >> 15) & 0x00010001u) * 0xffffu;
      v[24] = (u ^ mm) | (0x80008000u & ~mm);
    }
  }
  // thread max
  uint mx = 0;
#pragma unroll
  for (int i = 0; i < 25; i++) {
    uint a = v[i] & 0xffffu, b = v[i] >> 16;
    mx = a > mx ? a : mx;
    mx = b > mx ? b : mx;
  }
  smax[t] = (ushort)mx;
  if (t == 0) shC = 0;
  __syncthreads();

  // L = 100th largest of 256 thread maxima — ballot-popcount counting
  uint m0 = smax[lane], m1 = smax[lane + 64], m2 = smax[lane + 128], m3 = smax[lane + 192];
  uint lo = 0, hi = 65536;
  while (hi - lo > 1) {
    uint mid = (lo + hi) >> 1;
    int c = __popcll(__ballot(m0 >= mid)) + __popcll(__ballot(m1 >= mid)) +
            __popcll(__ballot(m2 >= mid)) + __popcll(__ballot(m3 >= mid));
    if (c >= KTOP) lo = mid; else hi = mid;
  }
  const uint L = lo;

  // ---- ballot compaction of keys >= L into LDS (1 atomic per wave) ----
  const unsigned long long ltm = (1ull << lane) - 1ull;
  int tot = 0;
#pragma unroll
  for (int i = 0; i < 25; i++) {
    tot += __popcll(__ballot((v[i] & 0xffffu) >= L));
    tot += __popcll(__ballot((v[i] >> 16) >= L));
  }
  int wb = 0;
  if (lane == 0) wb = atomicAdd(&shC, tot);
  wb = __shfl(wb, 0);
  int run = wb;
#pragma unroll
  for (int i = 0; i < 25; i++) {
    uint a = v[i] & 0xffffu, b = v[i] >> 16;
    unsigned long long ma = __ballot(a >= L);
    if (a >= L) { int p = run + __popcll(ma & ltm); if (p < LCAP2) list[p] = (ushort)a; }
    run += __popcll(ma);
    unsigned long long mb = __ballot(b >= L);
    if (b >= L) { int p = run + __popcll(mb & ltm); if (p < LCAP2) list[p] = (ushort)b; }
    run += __popcll(mb);
  }
  __syncthreads();
  const int C = shC;

  uint Tkey;
  if (C <= LCAP2) {                            // common path: ballot-count search
    uint lo2 = L, hi2 = 65536;
    while (hi2 - lo2 > 1) {
      uint mid = (lo2 + hi2) >> 1;
      int c = 0;
      for (int j = 0; j < C; j += 64) {
        bool p = (j + lane < C) && ((uint)list[j + lane] >= mid);
        c += __popcll(__ballot(p));
      }
      if (c >= KTOP) lo2 = mid; else hi2 = mid;
    }
    Tkey = lo2;
  } else {                                     // rare fallback: regs + barriers
    uint lo2 = L, hi2 = 65536;
    while (hi2 - lo2 > 1) {
      uint mid = (lo2 + hi2) >> 1;
      int c = 0;
#pragma unroll
      for (int i = 0; i < 25; i++) {
        c += ((v[i] & 0xffffu) >= mid) ? 1 : 0;
        c += ((v[i] >> 16) >= mid) ? 1 : 0;
      }
#pragma unroll
      for (int off = 32; off; off >>= 1) c += __shfl_xor(c, off);
      __syncthreads();
      if (lane == 0) ipart[t >> 6] = c;
      __syncthreads();
      c = ipart[0] + ipart[1] + ipart[2] + ipart[3];
      if (c >= KTOP) lo2 = mid; else hi2 = mid;
    }
    Tkey = lo2;
  }

  // emit segment top-100 multiset (m <= 99 strict keys + tie fill)
  if (t == 0) shM = 0;
  __syncthreads();
  ushort* dst = cand + (size_t)q * 1024 + seg * 128;
  if (C <= LCAP2) {
    for (int i = t; i < C; i += 256) {
      uint u = list[i];
      if (u > Tkey) { int p = atomicAdd(&shM, 1); dst[p] = (ushort)u; }
    }
  } else {
#pragma unroll
    for (int i = 0; i < 25; i++) {
      uint a = v[i] & 0xffffu, b = v[i] >> 16;
      if (a > Tkey) { int p = atomicAdd(&shM, 1); dst[p] = (ushort)a; }
      if (b > Tkey) { int p = atomicAdd(&shM, 1); dst[p] = (ushort)b; }
    }
  }
  __syncthreads();
  for (int i = shM + t; i < KTOP; i += 256) dst[i] = (ushort)Tkey;
}

// ---- merge 8x100 candidates + mean + energy -> out (1 wave / row) --------
__global__ __launch_bounds__(64) void topk_fin(const ushort* __restrict__ cand,
                                               const float* __restrict__ energy,
                                               float* __restrict__ out) {
  const int q = blockIdx.x;
  const int t = threadIdx.x;
  const ushort* row = cand + (size_t)q * 1024;
  ushort kk[16];
#pragma unroll
  for (int s = 0; s < 8; s++) {
    kk[2 * s]     = row[s * 128 + t];                                  // t < 100
    kk[2 * s + 1] = (t + 64 < KTOP) ? row[s * 128 + 64 + t] : (ushort)0;
  }
  uint lo = 0, hi = 65536;
  while (hi - lo > 1) {
    uint mid = (lo + hi) >> 1;
    int c = 0;
#pragma unroll
    for (int i = 0; i < 16; i++) c += ((uint)kk[i] >= mid) ? 1 : 0;
#pragma unroll
    for (int off = 32; off; off >>= 1) c += __shfl_xor(c, off);
    if (c >= KTOP) lo = mid; else hi = mid;
  }
  const uint T = lo;
  float s = 0.f;
  int m = 0;
#pragma unroll
  for (int i = 0; i < 16; i++) {
    if ((uint)kk[i] > T) { s += o16f(kk[i]); m++; }
  }
#pragma unroll
  for (int off = 32; off; off >>= 1) {
    s += __shfl_xor(s, off);
    m += __shfl_xor(m, off);
  }
  if (t == 0) {
    float total = s + (float)(KTOP - m) * o16f((ushort)T);
    out[q] = -(total * (1.0f / KTOP)) * energy[q];
  }
}

extern "C" void kernel_launch(void* const* d_in, const int* in_sizes, int n_in,
                              void* d_out, int out_size, void* d_ws, size_t ws_size,
                              hipStream_t stream) {
  const float* feature     = (const float*)d_in[0];
  const float* logit       = (const float*)d_in[1];
  const float* bank_feas   = (const float*)d_in[2];
  const float* bank_logits = (const float*)d_in[3];
  // d_in[4] is K (device scalar) — problem instance fixes K = 100 (KTOP).
  float* out = (float*)d_out;

  char* ws = (char*)d_ws;
  size_t off = 0;
  auto take = [&](size_t bytes) -> char* {
    char* p = ws + off;
    off = (off + bytes + 255) & ~(size_t)255;
    return p;
  };
  float*  energy = (float*)take((size_t)QROWS * 4);
  float*  conf   = (float*)take((size_t)NPAD * 4);
  ushort* a16    = (ushort*)take((size_t)QROWS * DDIM * 2);
  ushort* b16    = (ushort*)take((size_t)NPAD * DDIM * 2);
  ushort* sims   = (ushort*)take((size_t)QROWS * NPAD * 2);
  ushort* cand   = (ushort*)take((size_t)QROWS * 1024 * 2);
  if (off > ws_size) return;  // needs ~1.02 GB

  lse_rows <<<dim3((NBANK + 3) / 4), dim3(256), 0, stream>>>(bank_logits, conf, NBANK, CDIM);
  bank_sc  <<<dim3(NPAD / 4), dim3(256), 0, stream>>>(bank_feas, conf, b16);
  lse_rows <<<dim3(QROWS / 4), dim3(256), 0, stream>>>(logit, energy, QROWS, CDIM);
  feat_norm<<<dim3(QROWS / 4), dim3(256), 0, stream>>>(feature, a16);
  gemm_sims<<<dim3(GNWG), dim3(512), 0, stream>>>(a16, b16, sims);
  topk_seg <<<dim3(QROWS * 8), dim3(256), 0, stream>>>(sims, cand);
  topk_fin <<<dim3(QROWS), dim3(64), 0, stream>>>(cand, energy, out);
}